// Round 13
// baseline (552.531 us; speedup 1.0000x reference)
//
#include <hip/hip_runtime.h>
#include <hip/hip_bf16.h>
#include <math.h>

typedef __attribute__((ext_vector_type(8))) short short8;
typedef __attribute__((ext_vector_type(4))) float f32x4;

// Fast GELU via tanh-form reduced to a sigmoid, exp2-folded:
// gelu(x) = x - x/(1+e), e = 2^(x*(2.3022080 + 0.1029420*x^2))
// Max |err| vs exact erf-GELU ~3e-4 << bf16 ULP 2^-7. 1 v_exp + 1 v_rcp.
__device__ __forceinline__ float gelu_f(float x) {
  float s = x * x;
  float w = __builtin_fmaf(s, 0.10294196f, 2.30220795f);
  float e = __builtin_amdgcn_exp2f(x * w);
  float r = __builtin_amdgcn_rcpf(1.0f + e);
  return __builtin_fmaf(-x, r, x);
}

// ---------------------------------------------------------------------------
// Generic conv-as-implicit-GEMM fp32 (branch1 conv2/conv3 only)
// ---------------------------------------------------------------------------
template<bool TBL, bool GELU, bool TOOUT>
__global__ __launch_bounds__(256) void convgemm_k(
    const float* __restrict__ in, const float* __restrict__ w,
    const float* __restrict__ bns, const float* __restrict__ bnb,
    float* __restrict__ out,
    int Cin, int H, int W, int ks, int stride, int pad, int ls,
    int OH, int OW, int N, int K, int ch0) {
  __shared__ __align__(16) float sA[16][64];
  __shared__ __align__(16) float sB[16][64];
  __shared__ int sTbl[256];
  const int tid = threadIdx.x;
  if (TBL) {
    int kk2 = ks * ks;
    for (int k = tid; k < K; k += 256) {
      int ic = k / kk2, r = k - ic * kk2;
      sTbl[k] = (ic << 16) | ((r / ks) << 8) | (r % ks);
    }
  }
  const int m0 = blockIdx.x * 64, n0 = blockIdx.y * 64;
  const int mm = tid >> 2, kq = tid & 3;
  const int OHW = OH * OW, HW = H * W;
  int m = m0 + mm;
  int bI = m / OHW; int r = m - bI * OHW;
  int oh = r / OW;  int ow = r - oh * OW;
  const int ihBase = oh * stride - pad, iwBase = ow * stride - pad;
  const int inBase = bI * Cin * HW;
  const int tm = tid & 15, tn = tid >> 4;
  float acc[4][4] = {};
  for (int k0 = 0; k0 < K; k0 += 16) {
    __syncthreads();
#pragma unroll
    for (int i = 0; i < 4; ++i) {
      int kk = kq * 4 + i, k = k0 + kk;
      float v = 0.0f;
      if (k < K) {
        int ic, dy, dx;
        if (TBL) {
          int tv = sTbl[k]; ic = tv >> 16; dy = (tv >> 8) & 255; dx = tv & 255;
        } else {
          ic = k >> (2 * ls);
          int r2 = k & ((1 << (2 * ls)) - 1);
          dy = r2 >> ls; dx = r2 & ((1 << ls) - 1);
        }
        int ih = ihBase + dy, iw = iwBase + dx;
        if (ih >= 0 && ih < H && iw >= 0 && iw < W)
          v = in[inBase + ic * HW + ih * W + iw];
      }
      sA[kk][mm] = v;
    }
#pragma unroll
    for (int i = 0; i < 4; ++i) {
      int kk = kq * 4 + i, k = k0 + kk;
      int n = n0 + mm;
      float v = 0.0f;
      if (n < N && k < K) v = w[n * K + k];
      sB[kk][mm] = v;
    }
    __syncthreads();
#pragma unroll
    for (int kk = 0; kk < 16; ++kk) {
      float4 a4 = *(const float4*)&sA[kk][tm * 4];
      float4 b4 = *(const float4*)&sB[kk][tn * 4];
      acc[0][0] += a4.x * b4.x; acc[0][1] += a4.x * b4.y;
      acc[0][2] += a4.x * b4.z; acc[0][3] += a4.x * b4.w;
      acc[1][0] += a4.y * b4.x; acc[1][1] += a4.y * b4.y;
      acc[1][2] += a4.y * b4.z; acc[1][3] += a4.y * b4.w;
      acc[2][0] += a4.z * b4.x; acc[2][1] += a4.z * b4.y;
      acc[2][2] += a4.z * b4.z; acc[2][3] += a4.z * b4.w;
      acc[3][0] += a4.w * b4.x; acc[3][1] += a4.w * b4.y;
      acc[3][2] += a4.w * b4.z; acc[3][3] += a4.w * b4.w;
    }
  }
#pragma unroll
  for (int i = 0; i < 4; ++i) {
    int mI = m0 + tm * 4 + i;
    int bO = mI / OHW; int rr = mI - bO * OHW;
#pragma unroll
    for (int j = 0; j < 4; ++j) {
      int n = n0 + tn * 4 + j;
      if (n < N) {
        float v = acc[i][j] * bns[n] + bnb[n];
        if (GELU) v = gelu_f(v);
        if (TOOUT) {
          out[(bO * OHW + rr) * 768 + ch0 + n] = v;  // OHW==196
        } else {
          int oh2 = rr / OW, ow2 = rr - oh2 * OW;
          out[((bO * N + n) * OH + oh2) * OW + ow2] = v;
        }
      }
    }
  }
}

// ---------------------------------------------------------------------------
// NHWC bf16 implicit-GEMM conv via MFMA (branch2 conv1 + branch1 conv1).
// OUTMODE: 0 = NCHW fp32 (ch stride NVALID), 1 = NHWC bf16 (ch stride NVALID).
// ---------------------------------------------------------------------------
template<int CIN, int KS, int STRIDE, int PAD, int NN, int KP, bool GELU,
         int OUTMODE, int NVALID = NN>
__global__ __launch_bounds__(256) void nhwc_conv_mfma(
    const __hip_bfloat16* __restrict__ in, const __hip_bfloat16* __restrict__ wb,
    const float* __restrict__ bns, const float* __restrict__ bnb,
    float* __restrict__ out, int Hin, int Win, int OW, int OHW) {
  constexpr int K = KS * KS * CIN;
  constexpr int LROW = KP + 8;
  __shared__ __align__(16) __hip_bfloat16 sA[64][LROW];
  __shared__ __align__(16) __hip_bfloat16 sB[NN][LROW];
  const int tid = threadIdx.x;
  const float4 f4z = make_float4(0.f, 0.f, 0.f, 0.f);
  if constexpr (CIN == 4) {
    const int m = tid & 63, tg = tid >> 6;
    const int mg = blockIdx.x * 64 + m;
    const int bI = mg / OHW; int pix = mg - bI * OHW;
    const int oh = pix / OW, ow = pix - oh * OW;
    for (int dy = tg; dy < KS; dy += 4) {
      const int ih = oh * STRIDE - PAD + dy;
      __hip_bfloat16* dst = &sA[m][dy * KS * 4];
#pragma unroll
      for (int j = 0; j < KS; ++j) {
        int iw = ow * STRIDE - PAD + j;
        uint2 v = make_uint2(0u, 0u);
        if (ih >= 0 && ih < Hin && iw >= 0 && iw < Win)
          v = *(const uint2*)(in + (((size_t)bI * Hin + ih) * Win + iw) * 4);
        *(uint2*)(dst + j * 4) = v;
      }
    }
    if (tg == 3) {
      for (int c = K; c < KP; c += 4) *(uint2*)&sA[m][c] = make_uint2(0u, 0u);
    }
  } else {
    const int m = tid & 63, dy = tid >> 6;
    const int mg = blockIdx.x * 64 + m;
    const int bI = mg / OHW; int pix = mg - bI * OHW;
    const int oh = pix / OW, ow = pix - oh * OW;
    if (dy < KS) {
      const int ih = oh * STRIDE - PAD + dy;
      __hip_bfloat16* dst = &sA[m][dy * KS * CIN];
      if (ih < 0 || ih >= Hin) {
#pragma unroll
        for (int i = 0; i < KS * CIN / 8; ++i) ((float4*)dst)[i] = f4z;
      } else {
        const __hip_bfloat16* srow = in + ((size_t)bI * Hin + ih) * Win * CIN;
#pragma unroll
        for (int j = 0; j < KS; ++j) {
          int iw = ow * STRIDE - PAD + j;
          if (PAD > 0 && (iw < 0 || iw >= Win)) {
#pragma unroll
            for (int i = 0; i < CIN / 8; ++i) ((float4*)(dst + j * CIN))[i] = f4z;
          } else {
            const float4* s4 = (const float4*)(srow + (size_t)iw * CIN);
#pragma unroll
            for (int i = 0; i < CIN / 8; ++i) ((float4*)(dst + j * CIN))[i] = s4[i];
          }
        }
      }
    } else if (K < KP) {
#pragma unroll
      for (int c = K; c < KP + 8; c += 8) *(float4*)&sA[m][c] = f4z;
    }
  }
  {
    constexpr int NV = NN * KP / 8;
    const float4* w4 = (const float4*)wb;
    for (int i = tid; i < NV; i += 256) {
      int n = i / (KP / 8), c = i - n * (KP / 8);
      *(float4*)&sB[n][c * 8] = w4[i];
    }
  }
  __syncthreads();
  constexpr int NT = NN / 16;
  const int wave = tid >> 6, lane = tid & 63;
  const int fm = lane & 15, quad = lane >> 4;
  const int wm = wave * 16;
  f32x4 acc[NT] = {};
#pragma unroll
  for (int ks = 0; ks < KP / 32; ++ks) {
    short8 a = *(const short8*)&sA[wm + fm][ks * 32 + quad * 8];
#pragma unroll
    for (int j = 0; j < NT; ++j) {
      short8 b = *(const short8*)&sB[j * 16 + fm][ks * 32 + quad * 8];
      acc[j] = __builtin_amdgcn_mfma_f32_16x16x32_bf16(a, b, acc[j], 0, 0, 0);
    }
  }
  const int mg0 = blockIdx.x * 64 + wm + quad * 4;
  const int bI = mg0 / OHW, pix = mg0 - bI * OHW;
#pragma unroll
  for (int j = 0; j < NT; ++j) {
    int n = j * 16 + fm;
    if (n >= NVALID) continue;
    float s = bns[n], bb = bnb[n];
    float v[4];
#pragma unroll
    for (int e = 0; e < 4; ++e) {
      v[e] = acc[j][e] * s + bb;
      if (GELU) v[e] = gelu_f(v[e]);
    }
    if (OUTMODE == 0) {
      float4 v4 = make_float4(v[0], v[1], v[2], v[3]);
      *(float4*)&out[((size_t)(bI * NVALID + n)) * OHW + pix] = v4;
    } else {
      __hip_bfloat16* ob = (__hip_bfloat16*)out;
#pragma unroll
      for (int e = 0; e < 4; ++e)
        ob[((size_t)(bI * OHW + pix + e)) * NVALID + n] = (__hip_bfloat16)v[e];
    }
  }
}

// ---------------------------------------------------------------------------
// Tiled NHWC 5x5 conv (4->24, pad 2) + BN + GELU: x(bf16,4ch) -> C5b.
// ---------------------------------------------------------------------------
__global__ __launch_bounds__(256, 4) void conv5_tile_mfma(
    const __hip_bfloat16* __restrict__ in,   // xb [16,224,224,4] bf16
    const __hip_bfloat16* __restrict__ wb,   // [32][128] bf16 (rw_c5)
    const float* __restrict__ bns, const float* __restrict__ bnb,
    __hip_bfloat16* __restrict__ out) {      // C5b [16,224,224,24] NHWC bf16
  __shared__ __align__(16) __hip_bfloat16 sHalo[13][144];  // 12 rows + zero row
  __shared__ __align__(16) __hip_bfloat16 sW5[32][128];
  __shared__ float sS[24], sBb[24];
  const int tid = threadIdx.x;
  const int X0 = blockIdx.x * 32, Y0 = blockIdx.y * 8, b = blockIdx.z;
  {
    const float4* w4 = (const float4*)wb;  // 32*16 float4
    for (int i = tid; i < 512; i += 256) {
      int n = i >> 4, g = i & 15;
      *(float4*)&sW5[n][(g ^ (n & 7)) * 8] = w4[i];
    }
  }
  if (tid < 24) { sS[tid] = bns[tid]; sBb[tid] = bnb[tid]; }
  for (int i = tid; i < 468; i += 256) {
    int r = i / 36, p = i - r * 36;
    int iy = Y0 - 2 + r, ix = X0 - 2 + p;
    uint2 v = make_uint2(0u, 0u);
    if (r < 12 && iy >= 0 && iy < 224 && ix >= 0 && ix < 224)
      v = *(const uint2*)(in + (((size_t)b * 224 + iy) * 224 + ix) * 4);
    *(uint2*)&sHalo[r][p * 4] = v;   // row 12 stays zero (dy=5 pad target)
  }
  __syncthreads();
  const int wave = tid >> 6, lane = tid & 63;
  const int fm = lane & 15, quad = lane >> 4;
  f32x4 acc[4][2] = {};
#pragma unroll
  for (int ks = 0; ks < 4; ++ks) {
    const int k0 = ks * 32 + quad * 8;
    const int dy = k0 / 24, u = k0 - dy * 24;  // dy=5 only for k>=120 (zero wts)
    const int grp = ks * 4 + quad;
    short8 wfr[2];
#pragma unroll
    for (int cg = 0; cg < 2; ++cg) {
      int wr = cg * 16 + fm;
      wfr[cg] = *(const short8*)&sW5[wr][(grp ^ (wr & 7)) * 8];
    }
#pragma unroll
    for (int pg = 0; pg < 4; ++pg) {
      const int r = 2 * wave + (pg >> 1);       // tile output row
      const int c = (pg & 1) * 16 + fm;         // tile output col
      short8 pf = *(const short8*)&sHalo[r + dy][c * 4 + u];
#pragma unroll
      for (int cg = 0; cg < 2; ++cg)
        acc[pg][cg] = __builtin_amdgcn_mfma_f32_16x16x32_bf16(
            wfr[cg], pf, acc[pg][cg], 0, 0, 0);
    }
  }
#pragma unroll
  for (int pg = 0; pg < 4; ++pg) {
    const int row = Y0 + 2 * wave + (pg >> 1);
    const int col = X0 + (pg & 1) * 16 + fm;
    __hip_bfloat16* obase = out + (((size_t)b * 224 + row) * 224 + col) * 24;
#pragma unroll
    for (int cg = 0; cg < 2; ++cg) {
      const int ch0 = cg * 16 + quad * 4;
      if (ch0 < 24) {
        __hip_bfloat16 vb[4];
#pragma unroll
        for (int e = 0; e < 4; ++e) {
          float v = acc[pg][cg][e] * sS[ch0 + e] + sBb[ch0 + e];
          vb[e] = (__hip_bfloat16)gelu_f(v);
        }
        *(uint2*)&obase[ch0] = *(uint2*)vb;
      }
    }
  }
}

// ---------------------------------------------------------------------------
// Tiled NHWC 3x3 conv (24->48) + BN + GELU for the region2 input (conv3).
// ---------------------------------------------------------------------------
__global__ __launch_bounds__(256, 4) void conv3_tile_mfma(
    const __hip_bfloat16* __restrict__ in,   // [16,224,224,24] NHWC bf16
    const __hip_bfloat16* __restrict__ wb,   // [48][224] bf16 (reorder layout)
    const float* __restrict__ bns, const float* __restrict__ bnb,
    __hip_bfloat16* __restrict__ out) {      // [16,224,224,48] NHWC bf16
  __shared__ __align__(16) __hip_bfloat16 sIn[11][816];  // 10 halo rows + zero row
  __shared__ __align__(16) __hip_bfloat16 sB[48][232];   // +8 pad: 2-way banks
  __shared__ float sS[48], sBb[48];
  const int tid = threadIdx.x;
  const int X0 = blockIdx.x * 32, Y0 = blockIdx.y * 8, b = blockIdx.z;
  {
    const float4* w4 = (const float4*)wb;  // 48*28 float4
    for (int i = tid; i < 1344; i += 256) {
      int n = i / 28, c = i - n * 28;
      *(float4*)&sB[n][c * 8] = w4[i];
    }
  }
  if (tid < 48) { sS[tid] = bns[tid]; sBb[tid] = bnb[tid]; }
  for (int i = tid; i < 1020; i += 256) {
    int r = i / 102, c8 = i - r * 102;
    int p = c8 / 3;                      // pixel within the 34-wide halo row
    int iy = Y0 - 1 + r, ix = X0 - 1 + p;
    uint4 v = make_uint4(0u, 0u, 0u, 0u);
    if (iy >= 0 && iy < 224 && ix >= 0 && ix < 224)
      v = *(const uint4*)(in + (((size_t)b * 224 + iy) * 224 + ix) * 24 +
                          (c8 - p * 3) * 8);
    *(uint4*)&sIn[r][c8 * 8] = v;
  }
  for (int i = tid; i < 102; i += 256)
    *(uint4*)&sIn[10][i * 8] = make_uint4(0u, 0u, 0u, 0u);
  __syncthreads();
  const int wave = tid >> 6, lane = tid & 63;
  const int fm = lane & 15, quad = lane >> 4;
  f32x4 acc[4][3] = {};
#pragma unroll
  for (int ks = 0; ks < 7; ++ks) {
    const int k0 = ks * 32 + quad * 8;   // 8-elem run never crosses dy (72%8==0)
    const int dy = k0 / 72;              // 3 for the k=216..223 pad (zero wts)
    const int u = k0 - dy * 72;
    short8 wfr[3];
#pragma unroll
    for (int cg = 0; cg < 3; ++cg)
      wfr[cg] = *(const short8*)&sB[cg * 16 + fm][k0];
#pragma unroll
    for (int pg = 0; pg < 4; ++pg) {
      const int r = 2 * wave + (pg >> 1);       // tile output row
      const int c = (pg & 1) * 16 + fm;         // tile output col
      short8 pf = *(const short8*)&sIn[r + dy][c * 24 + u];
#pragma unroll
      for (int cg = 0; cg < 3; ++cg)
        acc[pg][cg] = __builtin_amdgcn_mfma_f32_16x16x32_bf16(
            wfr[cg], pf, acc[pg][cg], 0, 0, 0);
    }
  }
#pragma unroll
  for (int pg = 0; pg < 4; ++pg) {
    const int row = Y0 + 2 * wave + (pg >> 1);
    const int col = X0 + (pg & 1) * 16 + fm;
    __hip_bfloat16* obase = out + (((size_t)b * 224 + row) * 224 + col) * 48;
#pragma unroll
    for (int cg = 0; cg < 3; ++cg) {
      const int ch0 = cg * 16 + quad * 4;
      __hip_bfloat16 vb[4];
#pragma unroll
      for (int e = 0; e < 4; ++e) {
        const int ch = ch0 + e;
        float v = acc[pg][cg][e] * sS[ch] + sBb[ch];
        vb[e] = (__hip_bfloat16)gelu_f(v);
      }
      *(uint2*)&obase[ch0] = *(uint2*)vb;
    }
  }
}

// ---------------------------------------------------------------------------
// Fused RegionLayerDW for region2 (round-6 validated: bf16 sIn staging).
// ---------------------------------------------------------------------------
__global__ __launch_bounds__(256, 4) void region2_mfma(
    const __hip_bfloat16* __restrict__ in, const float* __restrict__ dww,
    const float* __restrict__ s1v, const float* __restrict__ b1v,
    const __hip_bfloat16* __restrict__ pwb,
    const float* __restrict__ s2v, const float* __restrict__ b2v,
    __hip_bfloat16* __restrict__ out) {
  __shared__ __align__(16) __hip_bfloat16 sIn[10][10][56];
  __shared__ __align__(16) __hip_bfloat16 sH[64][64];
  __shared__ __align__(16) __hip_bfloat16 sW[48][64];
  __shared__ float sDW[48][9];
  __shared__ float sS1[48], sB1[48], sS2[48], sB2[48];
  const int t = blockIdx.x, sb = blockIdx.y, b = blockIdx.z;
  const int gy = t >> 2, gx = t & 3;
  const int py0 = (sb / 7) * 8, px0 = (sb % 7) * 8;
  const int Y0 = gy * 56, X0 = gx * 56;
  const int tid = threadIdx.x;
  for (int i = tid; i < 48 * 8; i += 256) {
    int n = i >> 3, g = i & 7;
    float4 v = *(const float4*)&pwb[(size_t)(t * 48 + n) * 64 + g * 8];
    *(float4*)&sW[n][((g ^ (n & 7)) * 8)] = v;
  }
  for (int i = tid; i < 432; i += 256) ((float*)sDW)[i] = dww[t * 432 + i];
  if (tid < 48) {
    sS1[tid] = s1v[t * 48 + tid]; sB1[tid] = b1v[t * 48 + tid];
    sS2[tid] = s2v[t * 48 + tid]; sB2[tid] = b2v[t * 48 + tid];
  }
  for (int i = tid; i < 600; i += 256) {
    int px = i / 6, grp = i - px * 6;
    int r = px / 10, c = px - r * 10;
    int ly = py0 + r - 1, lx = px0 + c - 1;
    uint4 v = make_uint4(0u, 0u, 0u, 0u);
    if (ly >= 0 && ly < 56 && lx >= 0 && lx < 56)
      v = *(const uint4*)(in + (((size_t)b * 224 + Y0 + ly) * 224 + X0 + lx) * 48 +
                          grp * 8);
    *(uint4*)&sIn[r][c][grp * 8] = v;
  }
  __syncthreads();
  if (tid < 192) {
    const int cg = tid >> 4;
    const int rem = tid & 15;
    const int col = rem >> 1;
    const int rh = rem & 1;
    const int ch0 = cg * 4;
    float wv[4][9], s14[4], b14[4];
#pragma unroll
    for (int c4 = 0; c4 < 4; ++c4) {
#pragma unroll
      for (int q = 0; q < 9; ++q) wv[c4][q] = sDW[ch0 + c4][q];
      s14[c4] = sS1[ch0 + c4]; b14[c4] = sB1[ch0 + c4];
    }
    float win[3][12];
#pragma unroll
    for (int rr = 0; rr < 6; ++rr) {
      int r = rh * 4 + rr;
      float* wr = win[rr % 3];
#pragma unroll
      for (int cc = 0; cc < 3; ++cc) {
        uint2 u = *(const uint2*)&sIn[r][col + cc][ch0];
        wr[cc * 4 + 0] = __uint_as_float(u.x << 16);
        wr[cc * 4 + 1] = __uint_as_float(u.x & 0xffff0000u);
        wr[cc * 4 + 2] = __uint_as_float(u.y << 16);
        wr[cc * 4 + 3] = __uint_as_float(u.y & 0xffff0000u);
      }
      if (rr >= 2) {
        const float* ra = win[(rr - 2) % 3];
        const float* rb = win[(rr - 1) % 3];
        const float* rc = win[rr % 3];
        int px = (rh * 4 + rr - 2) * 8 + col;
        __hip_bfloat16 hv[4];
#pragma unroll
        for (int c4 = 0; c4 < 4; ++c4) {
          float a = ra[c4] * wv[c4][0] + ra[4 + c4] * wv[c4][1] + ra[8 + c4] * wv[c4][2]
                  + rb[c4] * wv[c4][3] + rb[4 + c4] * wv[c4][4] + rb[8 + c4] * wv[c4][5]
                  + rc[c4] * wv[c4][6] + rc[4 + c4] * wv[c4][7] + rc[8 + c4] * wv[c4][8];
          hv[c4] = (__hip_bfloat16)gelu_f(a * s14[c4] + b14[c4]);
        }
        *(uint2*)&sH[px][((cg >> 1) ^ (px & 7)) * 8 + (cg & 1) * 4] = *(uint2*)hv;
      }
    }
  } else {
    for (int i = tid - 192; i < 128; i += 64) {
      int px = i >> 1, g = 6 + (i & 1);
      *(float4*)&sH[px][(g ^ (px & 7)) * 8] = make_float4(0.f, 0.f, 0.f, 0.f);
    }
  }
  __syncthreads();
  const int wave = tid >> 6, lane = tid & 63;
  const int fm = lane & 15, quad = lane >> 4;
  const int px = wave * 16 + fm, pxk = px & 7;
  f32x4 acc[3] = {};
#pragma unroll
  for (int ks = 0; ks < 2; ++ks) {
    short8 hb = *(const short8*)&sH[px][((ks * 4 + quad) ^ pxk) * 8];
#pragma unroll
    for (int m = 0; m < 3; ++m) {
      int wr = m * 16 + fm;
      short8 wa = *(const short8*)&sW[wr][((ks * 4 + quad) ^ (wr & 7)) * 8];
      acc[m] = __builtin_amdgcn_mfma_f32_16x16x32_bf16(wa, hb, acc[m], 0, 0, 0);
    }
  }
  const int row = px >> 3, col = px & 7;
  __hip_bfloat16* obase =
      out + (((size_t)b * 224 + Y0 + py0 + row) * 224 + X0 + px0 + col) * 48;
#pragma unroll
  for (int m = 0; m < 3; ++m) {
    int ch0m = m * 16 + quad * 4;
    uint2 ru = *(const uint2*)&sIn[row + 1][col + 1][ch0m];
    float res[4];
    res[0] = __uint_as_float(ru.x << 16);
    res[1] = __uint_as_float(ru.x & 0xffff0000u);
    res[2] = __uint_as_float(ru.y << 16);
    res[3] = __uint_as_float(ru.y & 0xffff0000u);
    __hip_bfloat16 vb[4];
#pragma unroll
    for (int e = 0; e < 4; ++e) {
      int ch = ch0m + e;
      float v = acc[m][e] * sS2[ch] + sB2[ch] + res[e];
      vb[e] = (__hip_bfloat16)gelu_f(v);
    }
    *(uint2*)&obase[ch0m] = *(uint2*)vb;
  }
}

// ---------------------------------------------------------------------------
// Fused RegionLayerDW for region1 (round-6 validated): C=24, tile 32x32, G=7.
// ---------------------------------------------------------------------------
__global__ __launch_bounds__(256, 4) void region1_mfma(
    const __hip_bfloat16* __restrict__ in, const float* __restrict__ dww,
    const float* __restrict__ s1v, const float* __restrict__ b1v,
    const __hip_bfloat16* __restrict__ pwb,  // [49][24][32] bf16 K-padded
    const float* __restrict__ s2v, const float* __restrict__ b2v,
    __hip_bfloat16* __restrict__ out) {
  __shared__ __align__(16) __hip_bfloat16 sIn[10][10][24];
  __shared__ __align__(16) __hip_bfloat16 sH[64][32];
  __shared__ __align__(16) __hip_bfloat16 sW[32][32];
  __shared__ float sDW[24][9];
  __shared__ float sS1[24], sB1[24], sS2[24], sB2[24];
  const int t = blockIdx.x, sb = blockIdx.y, b = blockIdx.z;
  const int gy = t / 7, gx = t % 7;
  const int py0 = (sb >> 2) * 8, px0 = (sb & 3) * 8;
  const int Y0 = gy * 32, X0 = gx * 32;
  const int tid = threadIdx.x;
  for (int i = tid; i < 128; i += 256) {
    int n = i >> 2, g = i & 3;
    float4 v = make_float4(0.f, 0.f, 0.f, 0.f);
    if (n < 24) v = *(const float4*)&pwb[(size_t)(t * 24 + n) * 32 + g * 8];
    *(float4*)&sW[n][(g ^ (n & 3)) * 8] = v;
  }
  for (int i = tid; i < 216; i += 256) ((float*)sDW)[i] = dww[t * 216 + i];
  if (tid < 24) {
    sS1[tid] = s1v[t * 24 + tid]; sB1[tid] = b1v[t * 24 + tid];
    sS2[tid] = s2v[t * 24 + tid]; sB2[tid] = b2v[t * 24 + tid];
  }
  for (int i = tid; i < 300; i += 256) {
    int px = i / 3, grp = i - px * 3;
    int r = px / 10, c = px - r * 10;
    int ly = py0 + r - 1, lx = px0 + c - 1;
    uint4 v = make_uint4(0u, 0u, 0u, 0u);
    if (ly >= 0 && ly < 32 && lx >= 0 && lx < 32)
      v = *(const uint4*)(in + (((size_t)b * 224 + Y0 + ly) * 224 + X0 + lx) * 24 +
                          grp * 8);
    *(uint4*)&sIn[r][c][grp * 8] = v;
  }
  __syncthreads();
  if (tid < 192) {
    const int cg = tid >> 5;
    const int rem = tid & 31;
    const int col = rem >> 2;
    const int rq = rem & 3;          // output rows rq*2, rq*2+1
    const int ch0 = cg * 4;
    float wv[4][9], s14[4], b14[4];
#pragma unroll
    for (int c4 = 0; c4 < 4; ++c4) {
#pragma unroll
      for (int q = 0; q < 9; ++q) wv[c4][q] = sDW[ch0 + c4][q];
      s14[c4] = sS1[ch0 + c4]; b14[c4] = sB1[ch0 + c4];
    }
    float win[3][12];
#pragma unroll
    for (int rr = 0; rr < 4; ++rr) {
      int r = rq * 2 + rr;
      float* wr = win[rr % 3];
#pragma unroll
      for (int cc = 0; cc < 3; ++cc) {
        uint2 u = *(const uint2*)&sIn[r][col + cc][ch0];
        wr[cc * 4 + 0] = __uint_as_float(u.x << 16);
        wr[cc * 4 + 1] = __uint_as_float(u.x & 0xffff0000u);
        wr[cc * 4 + 2] = __uint_as_float(u.y << 16);
        wr[cc * 4 + 3] = __uint_as_float(u.y & 0xffff0000u);
      }
      if (rr >= 2) {
        const float* ra = win[(rr - 2) % 3];
        const float* rb = win[(rr - 1) % 3];
        const float* rc = win[rr % 3];
        int px = (rq * 2 + rr - 2) * 8 + col;
        __hip_bfloat16 hv[4];
#pragma unroll
        for (int c4 = 0; c4 < 4; ++c4) {
          float a = ra[c4] * wv[c4][0] + ra[4 + c4] * wv[c4][1] + ra[8 + c4] * wv[c4][2]
                  + rb[c4] * wv[c4][3] + rb[4 + c4] * wv[c4][4] + rb[8 + c4] * wv[c4][5]
                  + rc[c4] * wv[c4][6] + rc[4 + c4] * wv[c4][7] + rc[8 + c4] * wv[c4][8];
          hv[c4] = (__hip_bfloat16)gelu_f(a * s14[c4] + b14[c4]);
        }
        *(uint2*)&sH[px][((cg >> 1) ^ (px & 3)) * 8 + (cg & 1) * 4] = *(uint2*)hv;
      }
    }
  } else {
    // zero-pad sH k-group 3 (ch 24..31): 64 px, one float4 each
    int px = tid - 192;
    *(float4*)&sH[px][(3 ^ (px & 3)) * 8] = make_float4(0.f, 0.f, 0.f, 0.f);
  }
  __syncthreads();
  const int wave = tid >> 6, lane = tid & 63;
  const int fm = lane & 15, quad = lane >> 4;
  const int px = wave * 16 + fm;
  short8 hb = *(const short8*)&sH[px][(quad ^ (px & 3)) * 8];
  f32x4 acc[2] = {};
#pragma unroll
  for (int m = 0; m < 2; ++m) {
    int wr = m * 16 + fm;
    short8 wa = *(const short8*)&sW[wr][(quad ^ (wr & 3)) * 8];
    acc[m] = __builtin_amdgcn_mfma_f32_16x16x32_bf16(wa, hb, acc[m], 0, 0, 0);
  }
  const int row = px >> 3, col = px & 7;
  __hip_bfloat16* obase =
      out + (((size_t)b * 224 + Y0 + py0 + row) * 224 + X0 + px0 + col) * 24;
#pragma unroll
  for (int m = 0; m < 2; ++m) {
    int ch0m = m * 16 + quad * 4;
    if (ch0m < 24) {
      uint2 ru = *(const uint2*)&sIn[row + 1][col + 1][ch0m];
      float res[4];
      res[0] = __uint_as_float(ru.x << 16);
      res[1] = __uint_as_float(ru.x & 0xffff0000u);
      res[2] = __uint_as_float(ru.y << 16);
      res[3] = __uint_as_float(ru.y & 0xffff0000u);
      __hip_bfloat16 vb[4];
#pragma unroll
      for (int e = 0; e < 4; ++e) {
        int ch = ch0m + e;
        float v = acc[m][e] * sS2[ch] + sB2[ch] + res[e];
        vb[e] = (__hip_bfloat16)gelu_f(v);
      }
      *(uint2*)&obase[ch0m] = *(uint2*)vb;
    }
  }
}

// ---------------------------------------------------------------------------
// Patch-GEMM via MFMA (branch2-conv2 only now).
// ---------------------------------------------------------------------------
template<int PS, int IMGW, int KTOT, int KSL, bool ATOMIC>
__global__ __launch_bounds__(256) void patch_gemm_mfma(
    const __hip_bfloat16* __restrict__ A, const __hip_bfloat16* __restrict__ Wb,
    const float* __restrict__ scale, const float* __restrict__ bias,
    float* __restrict__ out, int M, int ch0) {
  constexpr int RUN = PS * 48;
  __shared__ __align__(16) __hip_bfloat16 sA[64][64];
  __shared__ __align__(16) __hip_bfloat16 sB[64][64];
  const int tid = threadIdx.x;
  const int m0 = blockIdx.x * 64, n0 = blockIdx.y * 64;
  const int kBase = blockIdx.z * KSL;
  const int mi = tid >> 2, seg = tid & 3;
  int m = m0 + mi; int mc = (m < M) ? m : (M - 1);
  int bI = mc / 196; int r = mc - bI * 196;
  int oh = r / 14, ow = r - oh * 14;
  const __hip_bfloat16* Abase =
      A + (((size_t)bI * IMGW + oh * PS) * IMGW + ow * PS) * 48;
  const __hip_bfloat16* Wrow = Wb + (size_t)(n0 + mi) * KTOT;
  const int wave = tid >> 6, lane = tid & 63;
  const int wm = (wave & 1) * 32, wn = (wave >> 1) * 32;
  const int fm = lane & 15, quad = lane >> 4;
  const int sw = fm & 7;
  f32x4 acc[2][2] = {};
  for (int k0 = kBase; k0 < kBase + KSL; k0 += 64) {
    int dy = k0 / RUN, rem = k0 - dy * RUN;
    __syncthreads();
    {
      const __hip_bfloat16* p = Abase + (size_t)dy * IMGW * 48 + rem + seg * 16;
      float4 v0 = *(const float4*)p;
      float4 v1 = *(const float4*)(p + 8);
      int key = mi & 7;
      *(float4*)&sA[mi][((seg * 2) ^ key) * 8] = v0;
      *(float4*)&sA[mi][((seg * 2 + 1) ^ key) * 8] = v1;
      const __hip_bfloat16* q = Wrow + k0 + seg * 16;
      float4 w0 = *(const float4*)q;
      float4 w1 = *(const float4*)(q + 8);
      *(float4*)&sB[mi][((seg * 2) ^ key) * 8] = w0;
      *(float4*)&sB[mi][((seg * 2 + 1) ^ key) * 8] = w1;
    }
    __syncthreads();
#pragma unroll
    for (int ks = 0; ks < 2; ++ks) {
      int cg = (ks * 4 + quad) ^ sw;
#pragma unroll
      for (int i = 0; i < 2; ++i) {
        short8 a = *(const short8*)&sA[wm + i * 16 + fm][cg * 8];
#pragma unroll
        for (int j = 0; j < 2; ++j) {
          short8 b = *(const short8*)&sB[wn + j * 16 + fm][cg * 8];
          acc[i][j] = __builtin_amdgcn_mfma_f32_16x16x32_bf16(a, b, acc[i][j], 0, 0, 0);
        }
      }
    }
  }
#pragma unroll
  for (int i = 0; i < 2; ++i) {
#pragma unroll
    for (int j = 0; j < 2; ++j) {
      int gn = n0 + wn + j * 16 + fm;
      float sc = scale[gn];
#pragma unroll
      for (int e = 0; e < 4; ++e) {
        int gm = m0 + wm + i * 16 + quad * 4 + e;
        if (gm < M) {
          if (ATOMIC)
            atomicAdd(&out[(size_t)gm * 768 + ch0 + gn], acc[i][j][e] * sc);
          else
            out[(size_t)gm * 768 + ch0 + gn] = acc[i][j][e] * sc + bias[gn];
        }
      }
    }
  }
}

// ---------------------------------------------------------------------------
// b3 patch-GEMM, FULL-N (256) tiles; M=64 rows, split-K z=8 (round-10 shape,
// the measured floor of the tiling family). + T14 async-STAGE register
// prefetch: next k-step's 10 float4 global loads issue BEFORE this step's
// MFMA cluster, so L2/L3 latency overlaps compute (only ILP available at
// ~1.2 blocks/CU). Same math/addresses, reordered issue.
// LDS: sA 8192 + sB 32768 = 40960 B exactly.
// ---------------------------------------------------------------------------
__global__ __launch_bounds__(256) void patch_gemm_b3(
    const __hip_bfloat16* __restrict__ A,    // T2b [16,224,224,48]
    const __hip_bfloat16* __restrict__ Wb,   // h3wb [256][12288]
    const float* __restrict__ scale, float* __restrict__ out) {
  __shared__ __align__(16) __hip_bfloat16 sA[64][64];
  __shared__ __align__(16) __hip_bfloat16 sB[256][64];
  const int tid = threadIdx.x;
  const int m0 = blockIdx.x * 64;
  const int kBase = blockIdx.y * 1536;
  const int mi = tid >> 2, seg = tid & 3;
  int m = m0 + mi;                  // M = 3136 = 49*64 exact, no guard
  int bI = m / 196; int r = m - bI * 196;
  int oh = r / 14, ow = r - oh * 14;
  const __hip_bfloat16* Abase =
      A + (((size_t)bI * 224 + oh * 16) * 224 + ow * 16) * 48;
  const __hip_bfloat16* Wrow = Wb + (size_t)tid * 12288;
  const int wave = tid >> 6, lane = tid & 63;
  const int wn = wave * 64;
  const int fm = lane & 15, quad = lane >> 4;
  const int sw = fm & 7;
  const int wkey = tid & 7;
  const int key = mi & 7;
  f32x4 acc[4][4] = {};
  float4 pa0, pa1, pw[8];
  // prologue: load first k-step into registers
  {
    int k0 = kBase;
    int dy = k0 / 768, rem = k0 - dy * 768;
    const __hip_bfloat16* p = Abase + (size_t)dy * 224 * 48 + rem + seg * 16;
    pa0 = *(const float4*)p;
    pa1 = *(const float4*)(p + 8);
    const __hip_bfloat16* q = Wrow + k0;
#pragma unroll
    for (int j = 0; j < 8; ++j) pw[j] = *(const float4*)(q + j * 8);
  }
  for (int k0 = kBase; k0 < kBase + 1536; k0 += 64) {
    __syncthreads();   // previous compute done reading LDS
    *(float4*)&sA[mi][((seg * 2) ^ key) * 8] = pa0;
    *(float4*)&sA[mi][((seg * 2 + 1) ^ key) * 8] = pa1;
#pragma unroll
    for (int j = 0; j < 8; ++j)
      *(float4*)&sB[tid][(j ^ wkey) * 8] = pw[j];
    __syncthreads();
    // T14: issue next k-step's loads BEFORE the MFMA cluster
    if (k0 + 64 < kBase + 1536) {
      int kn = k0 + 64;
      int dy = kn / 768, rem = kn - dy * 768;
      const __hip_bfloat16* p = Abase + (size_t)dy * 224 * 48 + rem + seg * 16;
      pa0 = *(const float4*)p;
      pa1 = *(const float4*)(p + 8);
      const __hip_bfloat16* q = Wrow + kn;
#pragma unroll
      for (int j = 0; j < 8; ++j) pw[j] = *(const float4*)(q + j * 8);
    }
#pragma unroll
    for (int ks = 0; ks < 2; ++ks) {
      int cg = (ks * 4 + quad) ^ sw;
      short8 a[4];
#pragma unroll
      for (int i = 0; i < 4; ++i)
        a[i] = *(const short8*)&sA[i * 16 + fm][cg * 8];
#pragma unroll
      for (int j = 0; j < 4; ++j) {
        short8 b = *(const short8*)&sB[wn + j * 16 + fm][cg * 8];
#pragma unroll
        for (int i = 0; i < 4; ++i)
          acc[i][j] = __builtin_amdgcn_mfma_f32_16x16x32_bf16(a[i], b, acc[i][j], 0, 0, 0);
      }
    }
  }
#pragma unroll
  for (int i = 0; i < 4; ++i) {
#pragma unroll
    for (int j = 0; j < 4; ++j) {
      int gn = wn + j * 16 + fm;
      float sc = scale[gn];
#pragma unroll
      for (int e = 0; e < 4; ++e) {
        int gm = m0 + i * 16 + quad * 4 + e;
        atomicAdd(&out[(size_t)gm * 768 + 512 + gn], acc[i][j][e] * sc);
      }
    }
  }
}

// ---------------------------------------------------------------------------
// MERGED prep kernel (h3wb LDS bounce, pitch-258) + h1w1b reorder.
// Block ranges: [0,3136) xcvt | [3136,3392) h3wb-bounce | [3392,3434) r2wb |
// [3434,3506) h2w1b | [3506,4274) h2w2b | [4274,4290) rw_c5 |
// [4290,4482) rw_pw | [4482,4629) rw_pw1 | [4629,4641) h1w1b |
// [4641,7777) init_b3.
// ---------------------------------------------------------------------------
__device__ __forceinline__ void reorder_wk_el(
    const float* __restrict__ w, __hip_bfloat16* __restrict__ o,
    int i, int N, int Cin, int ks, int KP) {
  if (i >= N * KP) return;
  int n = i / KP, k = i - n * KP;
  float v = 0.f;
  int K = ks * ks * Cin;
  if (k < K) {
    int dy = k / (ks * Cin); int r = k - dy * ks * Cin;
    int dx = r / Cin, ic = r - dx * Cin;
    v = w[((n * Cin + ic) * ks + dy) * ks + dx];
  }
  o[i] = (__hip_bfloat16)v;
}

__global__ __launch_bounds__(256) void prep_all(
    const float* __restrict__ x, __hip_bfloat16* __restrict__ xb,
    const float* __restrict__ h3_w, __hip_bfloat16* __restrict__ h3wb,
    const float* __restrict__ r2_w, __hip_bfloat16* __restrict__ r2wb,
    const float* __restrict__ h2_w1, __hip_bfloat16* __restrict__ h2w1b,
    const float* __restrict__ h2_w2, __hip_bfloat16* __restrict__ h2w2b,
    const float* __restrict__ r1_w, __hip_bfloat16* __restrict__ r1wb,
    const float* __restrict__ r2_pw, __hip_bfloat16* __restrict__ pw2wb,
    const float* __restrict__ r1_pw, __hip_bfloat16* __restrict__ pw1wb,
    const float* __restrict__ h1_w1, __hip_bfloat16* __restrict__ h1w1b,
    const float* __restrict__ h3_b, float* __restrict__ out) {
  __shared__ __hip_bfloat16 sL[48 * 258];   // pitch 258: bank stride 1 on gather
  const int blk = blockIdx.x, tid = threadIdx.x;
  if (blk < 3136) {                      // xcvt: [16,3,224,224] f32 -> NHWC4 bf16
    int i = blk * 256 + tid;             // 802816 exact
    int b = i / 50176, p = i - b * 50176;
    const float* src = x + (size_t)b * 150528 + p;
    __hip_bfloat16 v[4];
    v[0] = (__hip_bfloat16)src[0];
    v[1] = (__hip_bfloat16)src[50176];
    v[2] = (__hip_bfloat16)src[100352];
    v[3] = (__hip_bfloat16)0.0f;
    *(uint2*)&xb[(size_t)i * 4] = *(uint2*)v;
  } else if (blk < 3392) {               // h3wb: one n per block, LDS bounce
    int n = blk - 3136;                  // 0..255
    const float* src = h3_w + (size_t)n * 12288;   // [48][16][16] contiguous
    for (int j = tid; j < 12288; j += 256)
      sL[(j >> 8) * 258 + (j & 255)] = (__hip_bfloat16)src[j];
    __syncthreads();
    __hip_bfloat16* dst = h3wb + (size_t)n * 12288;
    for (int k = tid; k < 12288; k += 256) {
      int dy = k / 768, rem = k - dy * 768;
      int dx = rem / 48, ic = rem - dx * 48;
      dst[k] = sL[ic * 258 + dy * 16 + dx];
    }
  } else if (blk < 3434) {               // r2wb: N48 Cin24 ks3 KP224
    reorder_wk_el(r2_w, r2wb, (blk - 3392) * 256 + tid, 48, 24, 3, 224);
  } else if (blk < 3506) {               // h2w1b: N48 Cin24 ks4 KP384
    reorder_wk_el(h2_w1, h2w1b, (blk - 3434) * 256 + tid, 48, 24, 4, 384);
  } else if (blk < 4274) {               // h2w2b: N256 Cin48 ks4 KP768
    reorder_wk_el(h2_w2, h2w2b, (blk - 3506) * 256 + tid, 256, 48, 4, 768);
  } else if (blk < 4290) {               // rw_c5: [24,3,5,5] -> [32][128]
    int i = (blk - 4274) * 256 + tid;    // 4096 exact
    int n = i >> 7, k = i & 127;
    int dy = k / 24, u = k - dy * 24;
    float v = 0.f;
    if (n < 24 && dy < 5 && u < 20) {
      int dx = u >> 2, ic = u & 3;
      if (ic < 3) v = r1_w[((n * 3 + ic) * 5 + dy) * 5 + dx];
    }
    r1wb[i] = (__hip_bfloat16)v;
  } else if (blk < 4482) {               // rw_pw: [16][48][48] -> [16][48][64]
    int i = (blk - 4290) * 256 + tid;    // 49152 exact
    int t = i / 3072, r = i - t * 3072;
    int n = r >> 6, k = r & 63;
    float v = (k < 48) ? r2_pw[(t * 48 + n) * 48 + k] : 0.f;
    pw2wb[i] = (__hip_bfloat16)v;
  } else if (blk < 4629) {               // rw_pw1: [49][24][24] -> [49][24][32]
    int i = (blk - 4482) * 256 + tid;    // 37632 exact
    int t = i / 768, r = i - t * 768;
    int n = r >> 5, k = r & 31;
    float v = (k < 24) ? r1_pw[(t * 24 + n) * 24 + k] : 0.f;
    pw1wb[i] = (__hip_bfloat16)v;
  } else if (blk < 4641) {               // h1w1b: [48,3,4,4] -> [48][64]
    int i = (blk - 4629) * 256 + tid;    // 3072 exact
    int n = i >> 6, k = i & 63;          // k = dy*16 + dx*4 + ic (ch3 zero)
    int dy = k >> 4, r = k & 15;
    int dx = r >> 2, ic = r & 3;
    float v = 0.f;
    if (ic < 3) v = h1_w1[((n * 3 + ic) * 4 + dy) * 4 + dx];
    h1w1b[i] = (__hip_bfloat16)v;
  } else {                               // init_b3: out[:,512:768] = h3_b
    int i = (blk - 4641) * 256 + tid;    // 802816 exact
    int n = i & 255, bp = i >> 8;
    out[bp * 768 + 512 + n] = h3_b[n];
  }
}

// ---------------------------------------------------------------------------
extern "C" void kernel_launch(void* const* d_in, const int* in_sizes, int n_in,
                              void* d_out, int out_size, void* d_ws, size_t ws_size,
                              hipStream_t stream) {
  const float* x     = (const float*)d_in[0];
  const float* r1_w  = (const float*)d_in[1];
  const float* r1_s  = (const float*)d_in[2];
  const float* r1_b  = (const float*)d_in[3];
  const float* r1_dw = (const float*)d_in[4];
  const float* r1_s1 = (const float*)d_in[5];
  const float* r1_b1 = (const float*)d_in[6];
  const float* r1_pw = (const float*)d_in[7];
  const float* r1_s2 = (const float*)d_in[8];
  const float* r1_b2 = (const float*)d_in[9];
  const float* r2_w  = (const float*)d_in[10];
  const float* r2_s  = (const float*)d_in[11];
  const float* r2_b  = (const float*)d_in[12];
  const float* r2_dw = (const float*)d_in[13];
  const float* r2_s1 = (const float*)d_in[14];
  const float* r2_b1 = (const float*)d_in[15];
  const float* r2_pw = (const float*)d_in[16];
  const float* r2_s2 = (const float*)d_in[17];
  const float* r2_b2 = (const float*)d_in[18];
  const float* h1_w1 = (const float*)d_in[19];
  const float* h1_s1 = (const float*)d_in[20];
  const float* h1_b1 = (const float*)d_in[21];
  const float* h1_w2 = (const float*)d_in[22];
  const float* h1_s2 = (const float*)d_in[23];
  const float* h1_b2 = (const float*)d_in[24];
  const float* h1_w3 = (const float*)d_in[25];
  const float* h1_s3 = (const float*)d_in[26];
  const float* h1_b3 = (const float*)d_in[27];
  const float* h2_w1 = (const float*)d_in[28];
  const float* h2_s1 = (const float*)d_in[29];
  const float* h2_b1 = (const float*)d_in[30];
  const float* h2_w2 = (const float*)d_in[31];
  const float* h2_s2 = (const float*)d_in[32];
  const float* h2_b2 = (const float*)d_in[33];
  const float* h3_w  = (const float*)d_in[34];
  const float* h3_s  = (const float*)d_in[35];
  const float* h3_b  = (const float*)d_in[36];
  float* out = (float*)d_out;

  // Workspace (float-slot offsets). FULL-BATCH, peak < 256 MiB.
  float* F = (float*)d_ws;
  __hip_bfloat16* R1b   = (__hip_bfloat16*)F;                    // [16,224,224,24]
  __hip_bfloat16* C5b   = (__hip_bfloat16*)(F + 9633792);        // [16,224,224,24] (dead before conv3)
  __hip_bfloat16* T1b   = (__hip_bfloat16*)(F + 9633792);        // [16,224,224,48]
  __hip_bfloat16* T2b   = (__hip_bfloat16*)(F + 28901376);       // [16,224,224,48]
  __hip_bfloat16* h3wb  = (__hip_bfloat16*)(F + 48168960);       // [256][12288]
  __hip_bfloat16* r2wb  = (__hip_bfloat16*)(F + 49741824);       // [48][224]
  __hip_bfloat16* h2w1b = (__hip_bfloat16*)(F + 49747200);       // [48][384]
  __hip_bfloat16* pw2wb = (__hip_bfloat16*)(F + 49756416);       // [16][48][64]
  __hip_bfloat16* r1wb  = (__hip_bfloat16*)(F + 49780992);       // [32][128]
  __hip_bfloat16* h2w2b = (__hip_bfloat16*)(F + 49783040);       // [256][768]
  __hip_bfloat16* xb    = (__hip_bfloat16*)(F + 49881344);       // [16,224,224,4]
  __hip_bfloat16* S1b   = (__hip_bfloat16*)(F + 51486976);       // [16,56,56,48]
  float* S1             = F + 52691200;                          // [16,48,56,56]
  float* S2             = F + 55099648;                          // [16,48,28,28]
  __hip_bfloat16* pw1wb = (__hip_bfloat16*)(F + 55701760);       // [49][24][32]
  __hip_bfloat16* h1w1b = (__hip_bfloat16*)(F + 55720576);       // [48][64]

  dim3 blk(256);

  // ---- single merged prep dispatch (xcvt + all reorders + init_b3)
  prep_all<<<dim3(7777), blk, 0, stream>>>(
      x, xb, h3_w, h3wb, r2_w, r2wb, h2_w1, h2w1b, h2_w2, h2w2b,
      r1_w, r1wb, r2_pw, pw2wb, r1_pw, pw1wb, h1_w1, h1w1b, h3_b, out);

  // ---- region1 chain, FULL BATCH: conv5 (tiled MFMA) -> C5b, region1 -> R1b
  conv5_tile_mfma<<<dim3(7, 28, 16), blk, 0, stream>>>(
      xb, r1wb, r1_s, r1_b, C5b);
  region1_mfma<<<dim3(49, 16, 16), blk, 0, stream>>>(
      C5b, r1_dw, r1_s1, r1_b1, pw1wb, r1_s2, r1_b2, R1b);
  // ---- branch2: R1b -> S1b bf16 NHWC -> out[ch 256:512]
  nhwc_conv_mfma<24, 4, 4, 0, 48, 384, true, 1><<<dim3(784), blk, 0, stream>>>(
      R1b, h2w1b, h2_s1, h2_b1, (float*)S1b, 224, 224, 56, 3136);
  patch_gemm_mfma<4, 56, 768, 768, false><<<dim3(49, 4, 1), blk, 0, stream>>>(
      S1b, h2w2b, h2_s2, h2_b2, out, 3136, 256);
  // ---- branch1: xb -> S1 (MFMA, NCHW fp32 out) -> S2 -> out[ch 0:256]
  nhwc_conv_mfma<4, 4, 4, 0, 48, 64, true, 0><<<dim3(784), blk, 0, stream>>>(
      xb, h1w1b, h1_s1, h1_b1, S1, 224, 224, 56, 3136);
  convgemm_k<false, true, false><<<dim3(196, 1), blk, 0, stream>>>(
      S1, h1_w2, h1_s2, h1_b2, S2, 48, 56, 56, 2, 2, 0, 1, 28, 28, 48, 192, 0);
  convgemm_k<false, false, true><<<dim3(49, 4), blk, 0, stream>>>(
      S2, h1_w3, h1_s3, h1_b3, out, 48, 28, 28, 2, 2, 0, 1, 14, 14, 256, 192, 0);
  // ---- branch3 FULL BATCH: conv3(tiled) -> region2 -> b3 full-N GEMM (z=8)
  conv3_tile_mfma<<<dim3(7, 28, 16), blk, 0, stream>>>(
      R1b, r2wb, r2_s, r2_b, T1b);
  region2_mfma<<<dim3(16, 49, 16), blk, 0, stream>>>(
      T1b, r2_dw, r2_s1, r2_b1, pw2wb, r2_s2, r2_b2, T2b);
  patch_gemm_b3<<<dim3(49, 8), blk, 0, stream>>>(
      T2b, h3wb, h3_s, out);
  (void)in_sizes; (void)n_in; (void)out_size; (void)ws_size;
}

// Round 14
// 467.527 us; speedup vs baseline: 1.1818x; 1.1818x over previous
//
#include <hip/hip_runtime.h>
#include <hip/hip_bf16.h>
#include <math.h>

typedef __attribute__((ext_vector_type(8))) short short8;
typedef __attribute__((ext_vector_type(4))) float f32x4;

// Fast GELU via tanh-form reduced to a sigmoid, exp2-folded:
// gelu(x) = x - x/(1+e), e = 2^(x*(2.3022080 + 0.1029420*x^2))
// Max |err| vs exact erf-GELU ~3e-4 << bf16 ULP 2^-7. 1 v_exp + 1 v_rcp.
__device__ __forceinline__ float gelu_f(float x) {
  float s = x * x;
  float w = __builtin_fmaf(s, 0.10294196f, 2.30220795f);
  float e = __builtin_amdgcn_exp2f(x * w);
  float r = __builtin_amdgcn_rcpf(1.0f + e);
  return __builtin_fmaf(-x, r, x);
}

// ---------------------------------------------------------------------------
// Generic conv-as-implicit-GEMM fp32 (branch1 conv2/conv3 only)
// ---------------------------------------------------------------------------
template<bool TBL, bool GELU, bool TOOUT>
__global__ __launch_bounds__(256) void convgemm_k(
    const float* __restrict__ in, const float* __restrict__ w,
    const float* __restrict__ bns, const float* __restrict__ bnb,
    float* __restrict__ out,
    int Cin, int H, int W, int ks, int stride, int pad, int ls,
    int OH, int OW, int N, int K, int ch0) {
  __shared__ __align__(16) float sA[16][64];
  __shared__ __align__(16) float sB[16][64];
  __shared__ int sTbl[256];
  const int tid = threadIdx.x;
  if (TBL) {
    int kk2 = ks * ks;
    for (int k = tid; k < K; k += 256) {
      int ic = k / kk2, r = k - ic * kk2;
      sTbl[k] = (ic << 16) | ((r / ks) << 8) | (r % ks);
    }
  }
  const int m0 = blockIdx.x * 64, n0 = blockIdx.y * 64;
  const int mm = tid >> 2, kq = tid & 3;
  const int OHW = OH * OW, HW = H * W;
  int m = m0 + mm;
  int bI = m / OHW; int r = m - bI * OHW;
  int oh = r / OW;  int ow = r - oh * OW;
  const int ihBase = oh * stride - pad, iwBase = ow * stride - pad;
  const int inBase = bI * Cin * HW;
  const int tm = tid & 15, tn = tid >> 4;
  float acc[4][4] = {};
  for (int k0 = 0; k0 < K; k0 += 16) {
    __syncthreads();
#pragma unroll
    for (int i = 0; i < 4; ++i) {
      int kk = kq * 4 + i, k = k0 + kk;
      float v = 0.0f;
      if (k < K) {
        int ic, dy, dx;
        if (TBL) {
          int tv = sTbl[k]; ic = tv >> 16; dy = (tv >> 8) & 255; dx = tv & 255;
        } else {
          ic = k >> (2 * ls);
          int r2 = k & ((1 << (2 * ls)) - 1);
          dy = r2 >> ls; dx = r2 & ((1 << ls) - 1);
        }
        int ih = ihBase + dy, iw = iwBase + dx;
        if (ih >= 0 && ih < H && iw >= 0 && iw < W)
          v = in[inBase + ic * HW + ih * W + iw];
      }
      sA[kk][mm] = v;
    }
#pragma unroll
    for (int i = 0; i < 4; ++i) {
      int kk = kq * 4 + i, k = k0 + kk;
      int n = n0 + mm;
      float v = 0.0f;
      if (n < N && k < K) v = w[n * K + k];
      sB[kk][mm] = v;
    }
    __syncthreads();
#pragma unroll
    for (int kk = 0; kk < 16; ++kk) {
      float4 a4 = *(const float4*)&sA[kk][tm * 4];
      float4 b4 = *(const float4*)&sB[kk][tn * 4];
      acc[0][0] += a4.x * b4.x; acc[0][1] += a4.x * b4.y;
      acc[0][2] += a4.x * b4.z; acc[0][3] += a4.x * b4.w;
      acc[1][0] += a4.y * b4.x; acc[1][1] += a4.y * b4.y;
      acc[1][2] += a4.y * b4.z; acc[1][3] += a4.y * b4.w;
      acc[2][0] += a4.z * b4.x; acc[2][1] += a4.z * b4.y;
      acc[2][2] += a4.z * b4.z; acc[2][3] += a4.z * b4.w;
      acc[3][0] += a4.w * b4.x; acc[3][1] += a4.w * b4.y;
      acc[3][2] += a4.w * b4.z; acc[3][3] += a4.w * b4.w;
    }
  }
#pragma unroll
  for (int i = 0; i < 4; ++i) {
    int mI = m0 + tm * 4 + i;
    int bO = mI / OHW; int rr = mI - bO * OHW;
#pragma unroll
    for (int j = 0; j < 4; ++j) {
      int n = n0 + tn * 4 + j;
      if (n < N) {
        float v = acc[i][j] * bns[n] + bnb[n];
        if (GELU) v = gelu_f(v);
        if (TOOUT) {
          out[(bO * OHW + rr) * 768 + ch0 + n] = v;  // OHW==196
        } else {
          int oh2 = rr / OW, ow2 = rr - oh2 * OW;
          out[((bO * N + n) * OH + oh2) * OW + ow2] = v;
        }
      }
    }
  }
}

// ---------------------------------------------------------------------------
// NHWC bf16 implicit-GEMM conv via MFMA (branch2 conv1 + branch1 conv1).
// OUTMODE: 0 = NCHW fp32 (ch stride NVALID), 1 = NHWC bf16 (ch stride NVALID).
// ---------------------------------------------------------------------------
template<int CIN, int KS, int STRIDE, int PAD, int NN, int KP, bool GELU,
         int OUTMODE, int NVALID = NN>
__global__ __launch_bounds__(256) void nhwc_conv_mfma(
    const __hip_bfloat16* __restrict__ in, const __hip_bfloat16* __restrict__ wb,
    const float* __restrict__ bns, const float* __restrict__ bnb,
    float* __restrict__ out, int Hin, int Win, int OW, int OHW) {
  constexpr int K = KS * KS * CIN;
  constexpr int LROW = KP + 8;
  __shared__ __align__(16) __hip_bfloat16 sA[64][LROW];
  __shared__ __align__(16) __hip_bfloat16 sB[NN][LROW];
  const int tid = threadIdx.x;
  const float4 f4z = make_float4(0.f, 0.f, 0.f, 0.f);
  if constexpr (CIN == 4) {
    const int m = tid & 63, tg = tid >> 6;
    const int mg = blockIdx.x * 64 + m;
    const int bI = mg / OHW; int pix = mg - bI * OHW;
    const int oh = pix / OW, ow = pix - oh * OW;
    for (int dy = tg; dy < KS; dy += 4) {
      const int ih = oh * STRIDE - PAD + dy;
      __hip_bfloat16* dst = &sA[m][dy * KS * 4];
#pragma unroll
      for (int j = 0; j < KS; ++j) {
        int iw = ow * STRIDE - PAD + j;
        uint2 v = make_uint2(0u, 0u);
        if (ih >= 0 && ih < Hin && iw >= 0 && iw < Win)
          v = *(const uint2*)(in + (((size_t)bI * Hin + ih) * Win + iw) * 4);
        *(uint2*)(dst + j * 4) = v;
      }
    }
    if (tg == 3) {
      for (int c = K; c < KP; c += 4) *(uint2*)&sA[m][c] = make_uint2(0u, 0u);
    }
  } else {
    const int m = tid & 63, dy = tid >> 6;
    const int mg = blockIdx.x * 64 + m;
    const int bI = mg / OHW; int pix = mg - bI * OHW;
    const int oh = pix / OW, ow = pix - oh * OW;
    if (dy < KS) {
      const int ih = oh * STRIDE - PAD + dy;
      __hip_bfloat16* dst = &sA[m][dy * KS * CIN];
      if (ih < 0 || ih >= Hin) {
#pragma unroll
        for (int i = 0; i < KS * CIN / 8; ++i) ((float4*)dst)[i] = f4z;
      } else {
        const __hip_bfloat16* srow = in + ((size_t)bI * Hin + ih) * Win * CIN;
#pragma unroll
        for (int j = 0; j < KS; ++j) {
          int iw = ow * STRIDE - PAD + j;
          if (PAD > 0 && (iw < 0 || iw >= Win)) {
#pragma unroll
            for (int i = 0; i < CIN / 8; ++i) ((float4*)(dst + j * CIN))[i] = f4z;
          } else {
            const float4* s4 = (const float4*)(srow + (size_t)iw * CIN);
#pragma unroll
            for (int i = 0; i < CIN / 8; ++i) ((float4*)(dst + j * CIN))[i] = s4[i];
          }
        }
      }
    } else if (K < KP) {
#pragma unroll
      for (int c = K; c < KP + 8; c += 8) *(float4*)&sA[m][c] = f4z;
    }
  }
  {
    constexpr int NV = NN * KP / 8;
    const float4* w4 = (const float4*)wb;
    for (int i = tid; i < NV; i += 256) {
      int n = i / (KP / 8), c = i - n * (KP / 8);
      *(float4*)&sB[n][c * 8] = w4[i];
    }
  }
  __syncthreads();
  constexpr int NT = NN / 16;
  const int wave = tid >> 6, lane = tid & 63;
  const int fm = lane & 15, quad = lane >> 4;
  const int wm = wave * 16;
  f32x4 acc[NT] = {};
#pragma unroll
  for (int ks = 0; ks < KP / 32; ++ks) {
    short8 a = *(const short8*)&sA[wm + fm][ks * 32 + quad * 8];
#pragma unroll
    for (int j = 0; j < NT; ++j) {
      short8 b = *(const short8*)&sB[j * 16 + fm][ks * 32 + quad * 8];
      acc[j] = __builtin_amdgcn_mfma_f32_16x16x32_bf16(a, b, acc[j], 0, 0, 0);
    }
  }
  const int mg0 = blockIdx.x * 64 + wm + quad * 4;
  const int bI = mg0 / OHW, pix = mg0 - bI * OHW;
#pragma unroll
  for (int j = 0; j < NT; ++j) {
    int n = j * 16 + fm;
    if (n >= NVALID) continue;
    float s = bns[n], bb = bnb[n];
    float v[4];
#pragma unroll
    for (int e = 0; e < 4; ++e) {
      v[e] = acc[j][e] * s + bb;
      if (GELU) v[e] = gelu_f(v[e]);
    }
    if (OUTMODE == 0) {
      float4 v4 = make_float4(v[0], v[1], v[2], v[3]);
      *(float4*)&out[((size_t)(bI * NVALID + n)) * OHW + pix] = v4;
    } else {
      __hip_bfloat16* ob = (__hip_bfloat16*)out;
#pragma unroll
      for (int e = 0; e < 4; ++e)
        ob[((size_t)(bI * OHW + pix + e)) * NVALID + n] = (__hip_bfloat16)v[e];
    }
  }
}

// ---------------------------------------------------------------------------
// Tiled NHWC 5x5 conv (4->24, pad 2) + BN + GELU: x(bf16,4ch) -> C5b.
// ---------------------------------------------------------------------------
__global__ __launch_bounds__(256, 4) void conv5_tile_mfma(
    const __hip_bfloat16* __restrict__ in,   // xb [16,224,224,4] bf16
    const __hip_bfloat16* __restrict__ wb,   // [32][128] bf16 (rw_c5)
    const float* __restrict__ bns, const float* __restrict__ bnb,
    __hip_bfloat16* __restrict__ out) {      // C5b [16,224,224,24] NHWC bf16
  __shared__ __align__(16) __hip_bfloat16 sHalo[13][144];  // 12 rows + zero row
  __shared__ __align__(16) __hip_bfloat16 sW5[32][128];
  __shared__ float sS[24], sBb[24];
  const int tid = threadIdx.x;
  const int X0 = blockIdx.x * 32, Y0 = blockIdx.y * 8, b = blockIdx.z;
  {
    const float4* w4 = (const float4*)wb;  // 32*16 float4
    for (int i = tid; i < 512; i += 256) {
      int n = i >> 4, g = i & 15;
      *(float4*)&sW5[n][(g ^ (n & 7)) * 8] = w4[i];
    }
  }
  if (tid < 24) { sS[tid] = bns[tid]; sBb[tid] = bnb[tid]; }
  for (int i = tid; i < 468; i += 256) {
    int r = i / 36, p = i - r * 36;
    int iy = Y0 - 2 + r, ix = X0 - 2 + p;
    uint2 v = make_uint2(0u, 0u);
    if (r < 12 && iy >= 0 && iy < 224 && ix >= 0 && ix < 224)
      v = *(const uint2*)(in + (((size_t)b * 224 + iy) * 224 + ix) * 4);
    *(uint2*)&sHalo[r][p * 4] = v;   // row 12 stays zero (dy=5 pad target)
  }
  __syncthreads();
  const int wave = tid >> 6, lane = tid & 63;
  const int fm = lane & 15, quad = lane >> 4;
  f32x4 acc[4][2] = {};
#pragma unroll
  for (int ks = 0; ks < 4; ++ks) {
    const int k0 = ks * 32 + quad * 8;
    const int dy = k0 / 24, u = k0 - dy * 24;  // dy=5 only for k>=120 (zero wts)
    const int grp = ks * 4 + quad;
    short8 wfr[2];
#pragma unroll
    for (int cg = 0; cg < 2; ++cg) {
      int wr = cg * 16 + fm;
      wfr[cg] = *(const short8*)&sW5[wr][(grp ^ (wr & 7)) * 8];
    }
#pragma unroll
    for (int pg = 0; pg < 4; ++pg) {
      const int r = 2 * wave + (pg >> 1);       // tile output row
      const int c = (pg & 1) * 16 + fm;         // tile output col
      short8 pf = *(const short8*)&sHalo[r + dy][c * 4 + u];
#pragma unroll
      for (int cg = 0; cg < 2; ++cg)
        acc[pg][cg] = __builtin_amdgcn_mfma_f32_16x16x32_bf16(
            wfr[cg], pf, acc[pg][cg], 0, 0, 0);
    }
  }
#pragma unroll
  for (int pg = 0; pg < 4; ++pg) {
    const int row = Y0 + 2 * wave + (pg >> 1);
    const int col = X0 + (pg & 1) * 16 + fm;
    __hip_bfloat16* obase = out + (((size_t)b * 224 + row) * 224 + col) * 24;
#pragma unroll
    for (int cg = 0; cg < 2; ++cg) {
      const int ch0 = cg * 16 + quad * 4;
      if (ch0 < 24) {
        __hip_bfloat16 vb[4];
#pragma unroll
        for (int e = 0; e < 4; ++e) {
          float v = acc[pg][cg][e] * sS[ch0 + e] + sBb[ch0 + e];
          vb[e] = (__hip_bfloat16)gelu_f(v);
        }
        *(uint2*)&obase[ch0] = *(uint2*)vb;
      }
    }
  }
}

// ---------------------------------------------------------------------------
// Tiled NHWC 3x3 conv (24->48) + BN + GELU for the region2 input (conv3).
// ---------------------------------------------------------------------------
__global__ __launch_bounds__(256, 4) void conv3_tile_mfma(
    const __hip_bfloat16* __restrict__ in,   // [16,224,224,24] NHWC bf16
    const __hip_bfloat16* __restrict__ wb,   // [48][224] bf16 (reorder layout)
    const float* __restrict__ bns, const float* __restrict__ bnb,
    __hip_bfloat16* __restrict__ out) {      // [16,224,224,48] NHWC bf16
  __shared__ __align__(16) __hip_bfloat16 sIn[11][816];  // 10 halo rows + zero row
  __shared__ __align__(16) __hip_bfloat16 sB[48][232];   // +8 pad: 2-way banks
  __shared__ float sS[48], sBb[48];
  const int tid = threadIdx.x;
  const int X0 = blockIdx.x * 32, Y0 = blockIdx.y * 8, b = blockIdx.z;
  {
    const float4* w4 = (const float4*)wb;  // 48*28 float4
    for (int i = tid; i < 1344; i += 256) {
      int n = i / 28, c = i - n * 28;
      *(float4*)&sB[n][c * 8] = w4[i];
    }
  }
  if (tid < 48) { sS[tid] = bns[tid]; sBb[tid] = bnb[tid]; }
  for (int i = tid; i < 1020; i += 256) {
    int r = i / 102, c8 = i - r * 102;
    int p = c8 / 3;                      // pixel within the 34-wide halo row
    int iy = Y0 - 1 + r, ix = X0 - 1 + p;
    uint4 v = make_uint4(0u, 0u, 0u, 0u);
    if (iy >= 0 && iy < 224 && ix >= 0 && ix < 224)
      v = *(const uint4*)(in + (((size_t)b * 224 + iy) * 224 + ix) * 24 +
                          (c8 - p * 3) * 8);
    *(uint4*)&sIn[r][c8 * 8] = v;
  }
  for (int i = tid; i < 102; i += 256)
    *(uint4*)&sIn[10][i * 8] = make_uint4(0u, 0u, 0u, 0u);
  __syncthreads();
  const int wave = tid >> 6, lane = tid & 63;
  const int fm = lane & 15, quad = lane >> 4;
  f32x4 acc[4][3] = {};
#pragma unroll
  for (int ks = 0; ks < 7; ++ks) {
    const int k0 = ks * 32 + quad * 8;   // 8-elem run never crosses dy (72%8==0)
    const int dy = k0 / 72;              // 3 for the k=216..223 pad (zero wts)
    const int u = k0 - dy * 72;
    short8 wfr[3];
#pragma unroll
    for (int cg = 0; cg < 3; ++cg)
      wfr[cg] = *(const short8*)&sB[cg * 16 + fm][k0];
#pragma unroll
    for (int pg = 0; pg < 4; ++pg) {
      const int r = 2 * wave + (pg >> 1);       // tile output row
      const int c = (pg & 1) * 16 + fm;         // tile output col
      short8 pf = *(const short8*)&sIn[r + dy][c * 24 + u];
#pragma unroll
      for (int cg = 0; cg < 3; ++cg)
        acc[pg][cg] = __builtin_amdgcn_mfma_f32_16x16x32_bf16(
            wfr[cg], pf, acc[pg][cg], 0, 0, 0);
    }
  }
#pragma unroll
  for (int pg = 0; pg < 4; ++pg) {
    const int row = Y0 + 2 * wave + (pg >> 1);
    const int col = X0 + (pg & 1) * 16 + fm;
    __hip_bfloat16* obase = out + (((size_t)b * 224 + row) * 224 + col) * 48;
#pragma unroll
    for (int cg = 0; cg < 3; ++cg) {
      const int ch0 = cg * 16 + quad * 4;
      __hip_bfloat16 vb[4];
#pragma unroll
      for (int e = 0; e < 4; ++e) {
        const int ch = ch0 + e;
        float v = acc[pg][cg][e] * sS[ch] + sBb[ch];
        vb[e] = (__hip_bfloat16)gelu_f(v);
      }
      *(uint2*)&obase[ch0] = *(uint2*)vb;
    }
  }
}

// ---------------------------------------------------------------------------
// Fused RegionLayerDW for region2 (round-6 validated: bf16 sIn staging).
// ---------------------------------------------------------------------------
__global__ __launch_bounds__(256, 4) void region2_mfma(
    const __hip_bfloat16* __restrict__ in, const float* __restrict__ dww,
    const float* __restrict__ s1v, const float* __restrict__ b1v,
    const __hip_bfloat16* __restrict__ pwb,
    const float* __restrict__ s2v, const float* __restrict__ b2v,
    __hip_bfloat16* __restrict__ out) {
  __shared__ __align__(16) __hip_bfloat16 sIn[10][10][56];
  __shared__ __align__(16) __hip_bfloat16 sH[64][64];
  __shared__ __align__(16) __hip_bfloat16 sW[48][64];
  __shared__ float sDW[48][9];
  __shared__ float sS1[48], sB1[48], sS2[48], sB2[48];
  const int t = blockIdx.x, sb = blockIdx.y, b = blockIdx.z;
  const int gy = t >> 2, gx = t & 3;
  const int py0 = (sb / 7) * 8, px0 = (sb % 7) * 8;
  const int Y0 = gy * 56, X0 = gx * 56;
  const int tid = threadIdx.x;
  for (int i = tid; i < 48 * 8; i += 256) {
    int n = i >> 3, g = i & 7;
    float4 v = *(const float4*)&pwb[(size_t)(t * 48 + n) * 64 + g * 8];
    *(float4*)&sW[n][((g ^ (n & 7)) * 8)] = v;
  }
  for (int i = tid; i < 432; i += 256) ((float*)sDW)[i] = dww[t * 432 + i];
  if (tid < 48) {
    sS1[tid] = s1v[t * 48 + tid]; sB1[tid] = b1v[t * 48 + tid];
    sS2[tid] = s2v[t * 48 + tid]; sB2[tid] = b2v[t * 48 + tid];
  }
  for (int i = tid; i < 600; i += 256) {
    int px = i / 6, grp = i - px * 6;
    int r = px / 10, c = px - r * 10;
    int ly = py0 + r - 1, lx = px0 + c - 1;
    uint4 v = make_uint4(0u, 0u, 0u, 0u);
    if (ly >= 0 && ly < 56 && lx >= 0 && lx < 56)
      v = *(const uint4*)(in + (((size_t)b * 224 + Y0 + ly) * 224 + X0 + lx) * 48 +
                          grp * 8);
    *(uint4*)&sIn[r][c][grp * 8] = v;
  }
  __syncthreads();
  if (tid < 192) {
    const int cg = tid >> 4;
    const int rem = tid & 15;
    const int col = rem >> 1;
    const int rh = rem & 1;
    const int ch0 = cg * 4;
    float wv[4][9], s14[4], b14[4];
#pragma unroll
    for (int c4 = 0; c4 < 4; ++c4) {
#pragma unroll
      for (int q = 0; q < 9; ++q) wv[c4][q] = sDW[ch0 + c4][q];
      s14[c4] = sS1[ch0 + c4]; b14[c4] = sB1[ch0 + c4];
    }
    float win[3][12];
#pragma unroll
    for (int rr = 0; rr < 6; ++rr) {
      int r = rh * 4 + rr;
      float* wr = win[rr % 3];
#pragma unroll
      for (int cc = 0; cc < 3; ++cc) {
        uint2 u = *(const uint2*)&sIn[r][col + cc][ch0];
        wr[cc * 4 + 0] = __uint_as_float(u.x << 16);
        wr[cc * 4 + 1] = __uint_as_float(u.x & 0xffff0000u);
        wr[cc * 4 + 2] = __uint_as_float(u.y << 16);
        wr[cc * 4 + 3] = __uint_as_float(u.y & 0xffff0000u);
      }
      if (rr >= 2) {
        const float* ra = win[(rr - 2) % 3];
        const float* rb = win[(rr - 1) % 3];
        const float* rc = win[rr % 3];
        int px = (rh * 4 + rr - 2) * 8 + col;
        __hip_bfloat16 hv[4];
#pragma unroll
        for (int c4 = 0; c4 < 4; ++c4) {
          float a = ra[c4] * wv[c4][0] + ra[4 + c4] * wv[c4][1] + ra[8 + c4] * wv[c4][2]
                  + rb[c4] * wv[c4][3] + rb[4 + c4] * wv[c4][4] + rb[8 + c4] * wv[c4][5]
                  + rc[c4] * wv[c4][6] + rc[4 + c4] * wv[c4][7] + rc[8 + c4] * wv[c4][8];
          hv[c4] = (__hip_bfloat16)gelu_f(a * s14[c4] + b14[c4]);
        }
        *(uint2*)&sH[px][((cg >> 1) ^ (px & 7)) * 8 + (cg & 1) * 4] = *(uint2*)hv;
      }
    }
  } else {
    for (int i = tid - 192; i < 128; i += 64) {
      int px = i >> 1, g = 6 + (i & 1);
      *(float4*)&sH[px][(g ^ (px & 7)) * 8] = make_float4(0.f, 0.f, 0.f, 0.f);
    }
  }
  __syncthreads();
  const int wave = tid >> 6, lane = tid & 63;
  const int fm = lane & 15, quad = lane >> 4;
  const int px = wave * 16 + fm, pxk = px & 7;
  f32x4 acc[3] = {};
#pragma unroll
  for (int ks = 0; ks < 2; ++ks) {
    short8 hb = *(const short8*)&sH[px][((ks * 4 + quad) ^ pxk) * 8];
#pragma unroll
    for (int m = 0; m < 3; ++m) {
      int wr = m * 16 + fm;
      short8 wa = *(const short8*)&sW[wr][((ks * 4 + quad) ^ (wr & 7)) * 8];
      acc[m] = __builtin_amdgcn_mfma_f32_16x16x32_bf16(wa, hb, acc[m], 0, 0, 0);
    }
  }
  const int row = px >> 3, col = px & 7;
  __hip_bfloat16* obase =
      out + (((size_t)b * 224 + Y0 + py0 + row) * 224 + X0 + px0 + col) * 48;
#pragma unroll
  for (int m = 0; m < 3; ++m) {
    int ch0m = m * 16 + quad * 4;
    uint2 ru = *(const uint2*)&sIn[row + 1][col + 1][ch0m];
    float res[4];
    res[0] = __uint_as_float(ru.x << 16);
    res[1] = __uint_as_float(ru.x & 0xffff0000u);
    res[2] = __uint_as_float(ru.y << 16);
    res[3] = __uint_as_float(ru.y & 0xffff0000u);
    __hip_bfloat16 vb[4];
#pragma unroll
    for (int e = 0; e < 4; ++e) {
      int ch = ch0m + e;
      float v = acc[m][e] * sS2[ch] + sB2[ch] + res[e];
      vb[e] = (__hip_bfloat16)gelu_f(v);
    }
    *(uint2*)&obase[ch0m] = *(uint2*)vb;
  }
}

// ---------------------------------------------------------------------------
// Fused RegionLayerDW for region1 (round-6 validated): C=24, tile 32x32, G=7.
// ---------------------------------------------------------------------------
__global__ __launch_bounds__(256, 4) void region1_mfma(
    const __hip_bfloat16* __restrict__ in, const float* __restrict__ dww,
    const float* __restrict__ s1v, const float* __restrict__ b1v,
    const __hip_bfloat16* __restrict__ pwb,  // [49][24][32] bf16 K-padded
    const float* __restrict__ s2v, const float* __restrict__ b2v,
    __hip_bfloat16* __restrict__ out) {
  __shared__ __align__(16) __hip_bfloat16 sIn[10][10][24];
  __shared__ __align__(16) __hip_bfloat16 sH[64][32];
  __shared__ __align__(16) __hip_bfloat16 sW[32][32];
  __shared__ float sDW[24][9];
  __shared__ float sS1[24], sB1[24], sS2[24], sB2[24];
  const int t = blockIdx.x, sb = blockIdx.y, b = blockIdx.z;
  const int gy = t / 7, gx = t % 7;
  const int py0 = (sb >> 2) * 8, px0 = (sb & 3) * 8;
  const int Y0 = gy * 32, X0 = gx * 32;
  const int tid = threadIdx.x;
  for (int i = tid; i < 128; i += 256) {
    int n = i >> 2, g = i & 3;
    float4 v = make_float4(0.f, 0.f, 0.f, 0.f);
    if (n < 24) v = *(const float4*)&pwb[(size_t)(t * 24 + n) * 32 + g * 8];
    *(float4*)&sW[n][(g ^ (n & 3)) * 8] = v;
  }
  for (int i = tid; i < 216; i += 256) ((float*)sDW)[i] = dww[t * 216 + i];
  if (tid < 24) {
    sS1[tid] = s1v[t * 24 + tid]; sB1[tid] = b1v[t * 24 + tid];
    sS2[tid] = s2v[t * 24 + tid]; sB2[tid] = b2v[t * 24 + tid];
  }
  for (int i = tid; i < 300; i += 256) {
    int px = i / 3, grp = i - px * 3;
    int r = px / 10, c = px - r * 10;
    int ly = py0 + r - 1, lx = px0 + c - 1;
    uint4 v = make_uint4(0u, 0u, 0u, 0u);
    if (ly >= 0 && ly < 32 && lx >= 0 && lx < 32)
      v = *(const uint4*)(in + (((size_t)b * 224 + Y0 + ly) * 224 + X0 + lx) * 24 +
                          grp * 8);
    *(uint4*)&sIn[r][c][grp * 8] = v;
  }
  __syncthreads();
  if (tid < 192) {
    const int cg = tid >> 5;
    const int rem = tid & 31;
    const int col = rem >> 2;
    const int rq = rem & 3;          // output rows rq*2, rq*2+1
    const int ch0 = cg * 4;
    float wv[4][9], s14[4], b14[4];
#pragma unroll
    for (int c4 = 0; c4 < 4; ++c4) {
#pragma unroll
      for (int q = 0; q < 9; ++q) wv[c4][q] = sDW[ch0 + c4][q];
      s14[c4] = sS1[ch0 + c4]; b14[c4] = sB1[ch0 + c4];
    }
    float win[3][12];
#pragma unroll
    for (int rr = 0; rr < 4; ++rr) {
      int r = rq * 2 + rr;
      float* wr = win[rr % 3];
#pragma unroll
      for (int cc = 0; cc < 3; ++cc) {
        uint2 u = *(const uint2*)&sIn[r][col + cc][ch0];
        wr[cc * 4 + 0] = __uint_as_float(u.x << 16);
        wr[cc * 4 + 1] = __uint_as_float(u.x & 0xffff0000u);
        wr[cc * 4 + 2] = __uint_as_float(u.y << 16);
        wr[cc * 4 + 3] = __uint_as_float(u.y & 0xffff0000u);
      }
      if (rr >= 2) {
        const float* ra = win[(rr - 2) % 3];
        const float* rb = win[(rr - 1) % 3];
        const float* rc = win[rr % 3];
        int px = (rq * 2 + rr - 2) * 8 + col;
        __hip_bfloat16 hv[4];
#pragma unroll
        for (int c4 = 0; c4 < 4; ++c4) {
          float a = ra[c4] * wv[c4][0] + ra[4 + c4] * wv[c4][1] + ra[8 + c4] * wv[c4][2]
                  + rb[c4] * wv[c4][3] + rb[4 + c4] * wv[c4][4] + rb[8 + c4] * wv[c4][5]
                  + rc[c4] * wv[c4][6] + rc[4 + c4] * wv[c4][7] + rc[8 + c4] * wv[c4][8];
          hv[c4] = (__hip_bfloat16)gelu_f(a * s14[c4] + b14[c4]);
        }
        *(uint2*)&sH[px][((cg >> 1) ^ (px & 3)) * 8 + (cg & 1) * 4] = *(uint2*)hv;
      }
    }
  } else {
    // zero-pad sH k-group 3 (ch 24..31): 64 px, one float4 each
    int px = tid - 192;
    *(float4*)&sH[px][(3 ^ (px & 3)) * 8] = make_float4(0.f, 0.f, 0.f, 0.f);
  }
  __syncthreads();
  const int wave = tid >> 6, lane = tid & 63;
  const int fm = lane & 15, quad = lane >> 4;
  const int px = wave * 16 + fm;
  short8 hb = *(const short8*)&sH[px][(quad ^ (px & 3)) * 8];
  f32x4 acc[2] = {};
#pragma unroll
  for (int m = 0; m < 2; ++m) {
    int wr = m * 16 + fm;
    short8 wa = *(const short8*)&sW[wr][(quad ^ (wr & 3)) * 8];
    acc[m] = __builtin_amdgcn_mfma_f32_16x16x32_bf16(wa, hb, acc[m], 0, 0, 0);
  }
  const int row = px >> 3, col = px & 7;
  __hip_bfloat16* obase =
      out + (((size_t)b * 224 + Y0 + py0 + row) * 224 + X0 + px0 + col) * 24;
#pragma unroll
  for (int m = 0; m < 2; ++m) {
    int ch0m = m * 16 + quad * 4;
    if (ch0m < 24) {
      uint2 ru = *(const uint2*)&sIn[row + 1][col + 1][ch0m];
      float res[4];
      res[0] = __uint_as_float(ru.x << 16);
      res[1] = __uint_as_float(ru.x & 0xffff0000u);
      res[2] = __uint_as_float(ru.y << 16);
      res[3] = __uint_as_float(ru.y & 0xffff0000u);
      __hip_bfloat16 vb[4];
#pragma unroll
      for (int e = 0; e < 4; ++e) {
        int ch = ch0m + e;
        float v = acc[m][e] * sS2[ch] + sB2[ch] + res[e];
        vb[e] = (__hip_bfloat16)gelu_f(v);
      }
      *(uint2*)&obase[ch0m] = *(uint2*)vb;
    }
  }
}

// ---------------------------------------------------------------------------
// Patch-GEMM via MFMA (branch2-conv2 only now).
// ---------------------------------------------------------------------------
template<int PS, int IMGW, int KTOT, int KSL, bool ATOMIC>
__global__ __launch_bounds__(256) void patch_gemm_mfma(
    const __hip_bfloat16* __restrict__ A, const __hip_bfloat16* __restrict__ Wb,
    const float* __restrict__ scale, const float* __restrict__ bias,
    float* __restrict__ out, int M, int ch0) {
  constexpr int RUN = PS * 48;
  __shared__ __align__(16) __hip_bfloat16 sA[64][64];
  __shared__ __align__(16) __hip_bfloat16 sB[64][64];
  const int tid = threadIdx.x;
  const int m0 = blockIdx.x * 64, n0 = blockIdx.y * 64;
  const int kBase = blockIdx.z * KSL;
  const int mi = tid >> 2, seg = tid & 3;
  int m = m0 + mi; int mc = (m < M) ? m : (M - 1);
  int bI = mc / 196; int r = mc - bI * 196;
  int oh = r / 14, ow = r - oh * 14;
  const __hip_bfloat16* Abase =
      A + (((size_t)bI * IMGW + oh * PS) * IMGW + ow * PS) * 48;
  const __hip_bfloat16* Wrow = Wb + (size_t)(n0 + mi) * KTOT;
  const int wave = tid >> 6, lane = tid & 63;
  const int wm = (wave & 1) * 32, wn = (wave >> 1) * 32;
  const int fm = lane & 15, quad = lane >> 4;
  const int sw = fm & 7;
  f32x4 acc[2][2] = {};
  for (int k0 = kBase; k0 < kBase + KSL; k0 += 64) {
    int dy = k0 / RUN, rem = k0 - dy * RUN;
    __syncthreads();
    {
      const __hip_bfloat16* p = Abase + (size_t)dy * IMGW * 48 + rem + seg * 16;
      float4 v0 = *(const float4*)p;
      float4 v1 = *(const float4*)(p + 8);
      int key = mi & 7;
      *(float4*)&sA[mi][((seg * 2) ^ key) * 8] = v0;
      *(float4*)&sA[mi][((seg * 2 + 1) ^ key) * 8] = v1;
      const __hip_bfloat16* q = Wrow + k0 + seg * 16;
      float4 w0 = *(const float4*)q;
      float4 w1 = *(const float4*)(q + 8);
      *(float4*)&sB[mi][((seg * 2) ^ key) * 8] = w0;
      *(float4*)&sB[mi][((seg * 2 + 1) ^ key) * 8] = w1;
    }
    __syncthreads();
#pragma unroll
    for (int ks = 0; ks < 2; ++ks) {
      int cg = (ks * 4 + quad) ^ sw;
#pragma unroll
      for (int i = 0; i < 2; ++i) {
        short8 a = *(const short8*)&sA[wm + i * 16 + fm][cg * 8];
#pragma unroll
        for (int j = 0; j < 2; ++j) {
          short8 b = *(const short8*)&sB[wn + j * 16 + fm][cg * 8];
          acc[i][j] = __builtin_amdgcn_mfma_f32_16x16x32_bf16(a, b, acc[i][j], 0, 0, 0);
        }
      }
    }
  }
#pragma unroll
  for (int i = 0; i < 2; ++i) {
#pragma unroll
    for (int j = 0; j < 2; ++j) {
      int gn = n0 + wn + j * 16 + fm;
      float sc = scale[gn];
#pragma unroll
      for (int e = 0; e < 4; ++e) {
        int gm = m0 + wm + i * 16 + quad * 4 + e;
        if (gm < M) {
          if (ATOMIC)
            atomicAdd(&out[(size_t)gm * 768 + ch0 + gn], acc[i][j][e] * sc);
          else
            out[(size_t)gm * 768 + ch0 + gn] = acc[i][j][e] * sc + bias[gn];
        }
      }
    }
  }
}

// ---------------------------------------------------------------------------
// b3 patch-GEMM, FULL-N (256) tiles; M=64 rows, split-K z=8.
// Round-10 exact version: the measured floor of the tiling family (69.5 us).
// Each A element read by exactly ONE block; per-z W k-slice L3-resident.
// XOR-8 swizzle (0 bank conflicts measured). LDS: 8192 + 32768 = 40960 B.
// ---------------------------------------------------------------------------
__global__ __launch_bounds__(256) void patch_gemm_b3(
    const __hip_bfloat16* __restrict__ A,    // T2b [16,224,224,48]
    const __hip_bfloat16* __restrict__ Wb,   // h3wb [256][12288]
    const float* __restrict__ scale, float* __restrict__ out) {
  __shared__ __align__(16) __hip_bfloat16 sA[64][64];
  __shared__ __align__(16) __hip_bfloat16 sB[256][64];
  const int tid = threadIdx.x;
  const int m0 = blockIdx.x * 64;
  const int kBase = blockIdx.y * 1536;
  const int mi = tid >> 2, seg = tid & 3;
  int m = m0 + mi;                  // M = 3136 = 49*64 exact, no guard
  int bI = m / 196; int r = m - bI * 196;
  int oh = r / 14, ow = r - oh * 14;
  const __hip_bfloat16* Abase =
      A + (((size_t)bI * 224 + oh * 16) * 224 + ow * 16) * 48;
  const __hip_bfloat16* Wrow = Wb + (size_t)tid * 12288;
  const int wave = tid >> 6, lane = tid & 63;
  const int wn = wave * 64;
  const int fm = lane & 15, quad = lane >> 4;
  const int sw = fm & 7;
  const int wkey = tid & 7;
  f32x4 acc[4][4] = {};
  for (int k0 = kBase; k0 < kBase + 1536; k0 += 64) {
    int dy = k0 / 768, rem = k0 - dy * 768;   // RUN = 16*48 = 768
    __syncthreads();
    {
      const __hip_bfloat16* p = Abase + (size_t)dy * 224 * 48 + rem + seg * 16;
      float4 v0 = *(const float4*)p;
      float4 v1 = *(const float4*)(p + 8);
      int key = mi & 7;
      *(float4*)&sA[mi][((seg * 2) ^ key) * 8] = v0;
      *(float4*)&sA[mi][((seg * 2 + 1) ^ key) * 8] = v1;
      const __hip_bfloat16* q = Wrow + k0;    // one 128B run per lane
#pragma unroll
      for (int j = 0; j < 8; ++j) {
        float4 wv = *(const float4*)(q + j * 8);
        *(float4*)&sB[tid][(j ^ wkey) * 8] = wv;
      }
    }
    __syncthreads();
#pragma unroll
    for (int ks = 0; ks < 2; ++ks) {
      int cg = (ks * 4 + quad) ^ sw;
      short8 a[4];
#pragma unroll
      for (int i = 0; i < 4; ++i)
        a[i] = *(const short8*)&sA[i * 16 + fm][cg * 8];
#pragma unroll
      for (int j = 0; j < 4; ++j) {
        short8 b = *(const short8*)&sB[wn + j * 16 + fm][cg * 8];
#pragma unroll
        for (int i = 0; i < 4; ++i)
          acc[i][j] = __builtin_amdgcn_mfma_f32_16x16x32_bf16(a[i], b, acc[i][j], 0, 0, 0);
      }
    }
  }
#pragma unroll
  for (int i = 0; i < 4; ++i) {
#pragma unroll
    for (int j = 0; j < 4; ++j) {
      int gn = wn + j * 16 + fm;
      float sc = scale[gn];
#pragma unroll
      for (int e = 0; e < 4; ++e) {
        int gm = m0 + i * 16 + quad * 4 + e;
        atomicAdd(&out[(size_t)gm * 768 + 512 + gn], acc[i][j][e] * sc);
      }
    }
  }
}

// ---------------------------------------------------------------------------
// MERGED prep kernel (h3wb LDS bounce, pitch-258) + h1w1b reorder.
// Block ranges: [0,3136) xcvt | [3136,3392) h3wb-bounce | [3392,3434) r2wb |
// [3434,3506) h2w1b | [3506,4274) h2w2b | [4274,4290) rw_c5 |
// [4290,4482) rw_pw | [4482,4629) rw_pw1 | [4629,4641) h1w1b |
// [4641,7777) init_b3.
// ---------------------------------------------------------------------------
__device__ __forceinline__ void reorder_wk_el(
    const float* __restrict__ w, __hip_bfloat16* __restrict__ o,
    int i, int N, int Cin, int ks, int KP) {
  if (i >= N * KP) return;
  int n = i / KP, k = i - n * KP;
  float v = 0.f;
  int K = ks * ks * Cin;
  if (k < K) {
    int dy = k / (ks * Cin); int r = k - dy * ks * Cin;
    int dx = r / Cin, ic = r - dx * Cin;
    v = w[((n * Cin + ic) * ks + dy) * ks + dx];
  }
  o[i] = (__hip_bfloat16)v;
}

__global__ __launch_bounds__(256) void prep_all(
    const float* __restrict__ x, __hip_bfloat16* __restrict__ xb,
    const float* __restrict__ h3_w, __hip_bfloat16* __restrict__ h3wb,
    const float* __restrict__ r2_w, __hip_bfloat16* __restrict__ r2wb,
    const float* __restrict__ h2_w1, __hip_bfloat16* __restrict__ h2w1b,
    const float* __restrict__ h2_w2, __hip_bfloat16* __restrict__ h2w2b,
    const float* __restrict__ r1_w, __hip_bfloat16* __restrict__ r1wb,
    const float* __restrict__ r2_pw, __hip_bfloat16* __restrict__ pw2wb,
    const float* __restrict__ r1_pw, __hip_bfloat16* __restrict__ pw1wb,
    const float* __restrict__ h1_w1, __hip_bfloat16* __restrict__ h1w1b,
    const float* __restrict__ h3_b, float* __restrict__ out) {
  __shared__ __hip_bfloat16 sL[48 * 258];   // pitch 258: bank stride 1 on gather
  const int blk = blockIdx.x, tid = threadIdx.x;
  if (blk < 3136) {                      // xcvt: [16,3,224,224] f32 -> NHWC4 bf16
    int i = blk * 256 + tid;             // 802816 exact
    int b = i / 50176, p = i - b * 50176;
    const float* src = x + (size_t)b * 150528 + p;
    __hip_bfloat16 v[4];
    v[0] = (__hip_bfloat16)src[0];
    v[1] = (__hip_bfloat16)src[50176];
    v[2] = (__hip_bfloat16)src[100352];
    v[3] = (__hip_bfloat16)0.0f;
    *(uint2*)&xb[(size_t)i * 4] = *(uint2*)v;
  } else if (blk < 3392) {               // h3wb: one n per block, LDS bounce
    int n = blk - 3136;                  // 0..255
    const float* src = h3_w + (size_t)n * 12288;   // [48][16][16] contiguous
    for (int j = tid; j < 12288; j += 256)
      sL[(j >> 8) * 258 + (j & 255)] = (__hip_bfloat16)src[j];
    __syncthreads();
    __hip_bfloat16* dst = h3wb + (size_t)n * 12288;
    for (int k = tid; k < 12288; k += 256) {
      int dy = k / 768, rem = k - dy * 768;
      int dx = rem / 48, ic = rem - dx * 48;
      dst[k] = sL[ic * 258 + dy * 16 + dx];
    }
  } else if (blk < 3434) {               // r2wb: N48 Cin24 ks3 KP224
    reorder_wk_el(r2_w, r2wb, (blk - 3392) * 256 + tid, 48, 24, 3, 224);
  } else if (blk < 3506) {               // h2w1b: N48 Cin24 ks4 KP384
    reorder_wk_el(h2_w1, h2w1b, (blk - 3434) * 256 + tid, 48, 24, 4, 384);
  } else if (blk < 4274) {               // h2w2b: N256 Cin48 ks4 KP768
    reorder_wk_el(h2_w2, h2w2b, (blk - 3506) * 256 + tid, 256, 48, 4, 768);
  } else if (blk < 4290) {               // rw_c5: [24,3,5,5] -> [32][128]
    int i = (blk - 4274) * 256 + tid;    // 4096 exact
    int n = i >> 7, k = i & 127;
    int dy = k / 24, u = k - dy * 24;
    float v = 0.f;
    if (n < 24 && dy < 5 && u < 20) {
      int dx = u >> 2, ic = u & 3;
      if (ic < 3) v = r1_w[((n * 3 + ic) * 5 + dy) * 5 + dx];
    }
    r1wb[i] = (__hip_bfloat16)v;
  } else if (blk < 4482) {               // rw_pw: [16][48][48] -> [16][48][64]
    int i = (blk - 4290) * 256 + tid;    // 49152 exact
    int t = i / 3072, r = i - t * 3072;
    int n = r >> 6, k = r & 63;
    float v = (k < 48) ? r2_pw[(t * 48 + n) * 48 + k] : 0.f;
    pw2wb[i] = (__hip_bfloat16)v;
  } else if (blk < 4629) {               // rw_pw1: [49][24][24] -> [49][24][32]
    int i = (blk - 4482) * 256 + tid;    // 37632 exact
    int t = i / 768, r = i - t * 768;
    int n = r >> 5, k = r & 31;
    float v = (k < 24) ? r1_pw[(t * 24 + n) * 24 + k] : 0.f;
    pw1wb[i] = (__hip_bfloat16)v;
  } else if (blk < 4641) {               // h1w1b: [48,3,4,4] -> [48][64]
    int i = (blk - 4629) * 256 + tid;    // 3072 exact
    int n = i >> 6, k = i & 63;          // k = dy*16 + dx*4 + ic (ch3 zero)
    int dy = k >> 4, r = k & 15;
    int dx = r >> 2, ic = r & 3;
    float v = 0.f;
    if (ic < 3) v = h1_w1[((n * 3 + ic) * 4 + dy) * 4 + dx];
    h1w1b[i] = (__hip_bfloat16)v;
  } else {                               // init_b3: out[:,512:768] = h3_b
    int i = (blk - 4641) * 256 + tid;    // 802816 exact
    int n = i & 255, bp = i >> 8;
    out[bp * 768 + 512 + n] = h3_b[n];
  }
}

// ---------------------------------------------------------------------------
extern "C" void kernel_launch(void* const* d_in, const int* in_sizes, int n_in,
                              void* d_out, int out_size, void* d_ws, size_t ws_size,
                              hipStream_t stream) {
  const float* x     = (const float*)d_in[0];
  const float* r1_w  = (const float*)d_in[1];
  const float* r1_s  = (const float*)d_in[2];
  const float* r1_b  = (const float*)d_in[3];
  const float* r1_dw = (const float*)d_in[4];
  const float* r1_s1 = (const float*)d_in[5];
  const float* r1_b1 = (const float*)d_in[6];
  const float* r1_pw = (const float*)d_in[7];
  const float* r1_s2 = (const float*)d_in[8];
  const float* r1_b2 = (const float*)d_in[9];
  const float* r2_w  = (const float*)d_in[10];
  const float* r2_s  = (const float*)d_in[11];
  const float* r2_b  = (const float*)d_in[12];
  const float* r2_dw = (const float*)d_in[13];
  const float* r2_s1 = (const float*)d_in[14];
  const float* r2_b1 = (const float*)d_in[15];
  const float* r2_pw = (const float*)d_in[16];
  const float* r2_s2 = (const float*)d_in[17];
  const float* r2_b2 = (const float*)d_in[18];
  const float* h1_w1 = (const float*)d_in[19];
  const float* h1_s1 = (const float*)d_in[20];
  const float* h1_b1 = (const float*)d_in[21];
  const float* h1_w2 = (const float*)d_in[22];
  const float* h1_s2 = (const float*)d_in[23];
  const float* h1_b2 = (const float*)d_in[24];
  const float* h1_w3 = (const float*)d_in[25];
  const float* h1_s3 = (const float*)d_in[26];
  const float* h1_b3 = (const float*)d_in[27];
  const float* h2_w1 = (const float*)d_in[28];
  const float* h2_s1 = (const float*)d_in[29];
  const float* h2_b1 = (const float*)d_in[30];
  const float* h2_w2 = (const float*)d_in[31];
  const float* h2_s2 = (const float*)d_in[32];
  const float* h2_b2 = (const float*)d_in[33];
  const float* h3_w  = (const float*)d_in[34];
  const float* h3_s  = (const float*)d_in[35];
  const float* h3_b  = (const float*)d_in[36];
  float* out = (float*)d_out;

  // Workspace (float-slot offsets). FULL-BATCH, peak < 256 MiB.
  float* F = (float*)d_ws;
  __hip_bfloat16* R1b   = (__hip_bfloat16*)F;                    // [16,224,224,24]
  __hip_bfloat16* C5b   = (__hip_bfloat16*)(F + 9633792);        // [16,224,224,24] (dead before conv3)
  __hip_bfloat16* T1b   = (__hip_bfloat16*)(F + 9633792);        // [16,224,224,48]
  __hip_bfloat16* T2b   = (__hip_bfloat16*)(F + 28901376);       // [16,224,224,48]
  __hip_bfloat16* h3wb  = (__hip_bfloat16*)(F + 48168960);       // [256][12288]
  __hip_bfloat16* r2wb  = (__hip_bfloat16*)(F + 49741824);       // [48][224]
  __hip_bfloat16* h2w1b = (__hip_bfloat16*)(F + 49747200);       // [48][384]
  __hip_bfloat16* pw2wb = (__hip_bfloat16*)(F + 49756416);       // [16][48][64]
  __hip_bfloat16* r1wb  = (__hip_bfloat16*)(F + 49780992);       // [32][128]
  __hip_bfloat16* h2w2b = (__hip_bfloat16*)(F + 49783040);       // [256][768]
  __hip_bfloat16* xb    = (__hip_bfloat16*)(F + 49881344);       // [16,224,224,4]
  __hip_bfloat16* S1b   = (__hip_bfloat16*)(F + 51486976);       // [16,56,56,48]
  float* S1             = F + 52691200;                          // [16,48,56,56]
  float* S2             = F + 55099648;                          // [16,48,28,28]
  __hip_bfloat16* pw1wb = (__hip_bfloat16*)(F + 55701760);       // [49][24][32]
  __hip_bfloat16* h1w1b = (__hip_bfloat16*)(F + 55720576);       // [48][64]

  dim3 blk(256);

  // ---- single merged prep dispatch (xcvt + all reorders + init_b3)
  prep_all<<<dim3(7777), blk, 0, stream>>>(
      x, xb, h3_w, h3wb, r2_w, r2wb, h2_w1, h2w1b, h2_w2, h2w2b,
      r1_w, r1wb, r2_pw, pw2wb, r1_pw, pw1wb, h1_w1, h1w1b, h3_b, out);

  // ---- region1 chain, FULL BATCH: conv5 (tiled MFMA) -> C5b, region1 -> R1b
  conv5_tile_mfma<<<dim3(7, 28, 16), blk, 0, stream>>>(
      xb, r1wb, r1_s, r1_b, C5b);
  region1_mfma<<<dim3(49, 16, 16), blk, 0, stream>>>(
      C5b, r1_dw, r1_s1, r1_b1, pw1wb, r1_s2, r1_b2, R1b);
  // ---- branch2: R1b -> S1b bf16 NHWC -> out[ch 256:512]
  nhwc_conv_mfma<24, 4, 4, 0, 48, 384, true, 1><<<dim3(784), blk, 0, stream>>>(
      R1b, h2w1b, h2_s1, h2_b1, (float*)S1b, 224, 224, 56, 3136);
  patch_gemm_mfma<4, 56, 768, 768, false><<<dim3(49, 4, 1), blk, 0, stream>>>(
      S1b, h2w2b, h2_s2, h2_b2, out, 3136, 256);
  // ---- branch1: xb -> S1 (MFMA, NCHW fp32 out) -> S2 -> out[ch 0:256]
  nhwc_conv_mfma<4, 4, 4, 0, 48, 64, true, 0><<<dim3(784), blk, 0, stream>>>(
      xb, h1w1b, h1_s1, h1_b1, S1, 224, 224, 56, 3136);
  convgemm_k<false, true, false><<<dim3(196, 1), blk, 0, stream>>>(
      S1, h1_w2, h1_s2, h1_b2, S2, 48, 56, 56, 2, 2, 0, 1, 28, 28, 48, 192, 0);
  convgemm_k<false, false, true><<<dim3(49, 4), blk, 0, stream>>>(
      S2, h1_w3, h1_s3, h1_b3, out, 48, 28, 28, 2, 2, 0, 1, 14, 14, 256, 192, 0);
  // ---- branch3 FULL BATCH: conv3(tiled) -> region2 -> b3 full-N GEMM (z=8)
  conv3_tile_mfma<<<dim3(7, 28, 16), blk, 0, stream>>>(
      R1b, r2wb, r2_s, r2_b, T1b);
  region2_mfma<<<dim3(16, 49, 16), blk, 0, stream>>>(
      T1b, r2_dw, r2_s1, r2_b1, pw2wb, r2_s2, r2_b2, T2b);
  patch_gemm_b3<<<dim3(49, 8), blk, 0, stream>>>(
      T2b, h3wb, h3_s, out);
  (void)in_sizes; (void)n_in; (void)out_size; (void)ws_size;
}